// Round 7
// baseline (3770.758 us; speedup 1.0000x reference)
//
#include <hip/hip_runtime.h>
#include <hip/hip_bf16.h>

// JetGNN: 2-layer SAGEConv(mean) + ReLU + global_mean_pool + Linear(64->2)
// R1: hierarchical scan. R2: bucketed counting-sort CSR build.
// R3: run-flush pool (50MB->4MB atomics). R4: agg x4 unroll WIN (~95us);
//     forced weight VGPR arrays BAD (VGPR 204, occ 11.5%).
// R5/R6: LDS weights (stride 68, conflict-free) -- but VGPR STILL 204:
//     compiler fully unrolled the STRIP=16 loop and hoisted ~48 float4
//     feature loads. R7: '#pragma unroll 1' on the strip loop +
//     __launch_bounds__(256,4). Live set/iter ~40 VGPR -> 4 blocks/CU.

#define WS_ALIGN 64
#define EPB 4096          // edges per block in bucket_scatter (256 thr x 16)
#define BSHIFT 10         // 1024 nodes per bucket
#define BNODES 1024

// ---------- pooling counts ----------

__global__ void cnt_kernel(const int* __restrict__ batch, int* __restrict__ cnt, int N) {
    int i = blockIdx.x * blockDim.x + threadIdx.x;
    if (i < N) atomicAdd(&cnt[batch[i]], 1);
}

// ---------- bucketed CSR construction ----------

__global__ __launch_bounds__(256) void bucket_hist_kernel(const int* __restrict__ dst,
                                                          int* __restrict__ bucketCount, int E) {
    __shared__ int hist[256];
    const int t = threadIdx.x;
    hist[t] = 0;
    __syncthreads();
    for (int e = blockIdx.x * blockDim.x + t; e < E; e += gridDim.x * blockDim.x)
        atomicAdd(&hist[dst[e] >> BSHIFT], 1);
    __syncthreads();
    if (hist[t] > 0) atomicAdd(&bucketCount[t], hist[t]);
}

__global__ __launch_bounds__(256) void bucket_scan_kernel(const int* __restrict__ bucketCount,
                                                          int* __restrict__ bucketBase,
                                                          int* __restrict__ bucketCursor,
                                                          int NB, int E) {
    __shared__ int s[256];
    const int t = threadIdx.x;
    int v = (t < NB) ? bucketCount[t] : 0;
    s[t] = v;
    __syncthreads();
    for (int off = 1; off < 256; off <<= 1) {
        int u = (t >= off) ? s[t - off] : 0;
        __syncthreads();
        s[t] += u;
        __syncthreads();
    }
    int excl = s[t] - v;
    if (t < NB) { bucketBase[t] = excl; bucketCursor[t] = excl; }
    if (t == 0) bucketBase[NB] = E;
}

__global__ __launch_bounds__(256) void bucket_scatter_kernel(const int* __restrict__ src,
                                                             const int* __restrict__ dst,
                                                             int* __restrict__ bucketCursor,
                                                             unsigned* __restrict__ bucketData,
                                                             int E, int NB) {
    __shared__ int hist[256];
    __shared__ int cur[256];
    const int t = threadIdx.x;
    hist[t] = 0;
    __syncthreads();
    const int eBase = blockIdx.x * EPB + t;
    int s[16], b[16], dl[16];
#pragma unroll
    for (int j = 0; j < 16; ++j) {
        int e = eBase + j * 256;
        if (e < E) {
            int d = dst[e];
            s[j]  = src[e];
            b[j]  = d >> BSHIFT;
            dl[j] = d & (BNODES - 1);
            atomicAdd(&hist[b[j]], 1);
        } else {
            b[j] = -1;
        }
    }
    __syncthreads();
    if (t < NB && hist[t] > 0) cur[t] = atomicAdd(&bucketCursor[t], hist[t]);
    __syncthreads();
#pragma unroll
    for (int j = 0; j < 16; ++j) {
        if (b[j] >= 0) {
            int pos = atomicAdd(&cur[b[j]], 1);
            bucketData[pos] = ((unsigned)s[j] << BSHIFT) | (unsigned)dl[j];
        }
    }
}

__global__ __launch_bounds__(256) void csr_build_kernel(const unsigned* __restrict__ bucketData,
                                                        const int* __restrict__ bucketBase,
                                                        int* __restrict__ offsets,
                                                        int* __restrict__ csr_src,
                                                        int N, int E, int NB) {
    __shared__ int cnt[BNODES];
    __shared__ int sscan[256];
    __shared__ int cur[BNODES];
    const int t   = threadIdx.x;
    const int bkt = blockIdx.x;
    const int beg = bucketBase[bkt];
    const int end = bucketBase[bkt + 1];
    for (int i = t; i < BNODES; i += 256) cnt[i] = 0;
    __syncthreads();
    for (int k = beg + t; k < end; k += 256)
        atomicAdd(&cnt[bucketData[k] & (BNODES - 1)], 1);
    __syncthreads();
    int local[4];
    int sum = 0;
#pragma unroll
    for (int j = 0; j < 4; ++j) { local[j] = sum; sum += cnt[t * 4 + j]; }
    sscan[t] = sum;
    __syncthreads();
    for (int off = 1; off < 256; off <<= 1) {
        int v = (t >= off) ? sscan[t - off] : 0;
        __syncthreads();
        sscan[t] += v;
        __syncthreads();
    }
    int base = (t > 0) ? sscan[t - 1] : 0;
#pragma unroll
    for (int j = 0; j < 4; ++j) cur[t * 4 + j] = base + local[j];
    __syncthreads();
    for (int i = t; i < BNODES; i += 256) {
        int node = (bkt << BSHIFT) + i;
        if (node <= N) offsets[node] = beg + cur[i];
    }
    if (bkt == NB - 1 && t == 0 && (NB << BSHIFT) == N) offsets[N] = E;
    __syncthreads();
    for (int k = beg + t; k < end; k += 256) {
        unsigned v = bucketData[k];
        int d   = (int)(v & (BNODES - 1));
        int pos = beg + atomicAdd(&cur[d], 1);
        csr_src[pos] = (int)(v >> BSHIFT);
    }
}

// ---------- mean aggregation (node-parallel, D/4 threads per node) ----------
// R4: neighbor loop unrolled x4 -> 4 independent gathers in flight (WIN ~95us).

template <int D>
__global__ void agg_kernel(const float* __restrict__ feat,
                           const int* __restrict__ csr_src,
                           const int* __restrict__ offsets,
                           float* __restrict__ agg, int N) {
    constexpr int TPN = D / 4;
    int tid  = blockIdx.x * blockDim.x + threadIdx.x;
    int node = tid / TPN;
    int part = tid % TPN;
    if (node >= N) return;
    const int beg = offsets[node];
    const int end = offsets[node + 1];
    float4 acc = make_float4(0.f, 0.f, 0.f, 0.f);
    int k = beg;
    for (; k + 4 <= end; k += 4) {
        const int s0 = csr_src[k + 0];
        const int s1 = csr_src[k + 1];
        const int s2 = csr_src[k + 2];
        const int s3 = csr_src[k + 3];
        const float4 v0 = *reinterpret_cast<const float4*>(feat + (size_t)s0 * D + part * 4);
        const float4 v1 = *reinterpret_cast<const float4*>(feat + (size_t)s1 * D + part * 4);
        const float4 v2 = *reinterpret_cast<const float4*>(feat + (size_t)s2 * D + part * 4);
        const float4 v3 = *reinterpret_cast<const float4*>(feat + (size_t)s3 * D + part * 4);
        acc.x += (v0.x + v1.x) + (v2.x + v3.x);
        acc.y += (v0.y + v1.y) + (v2.y + v3.y);
        acc.z += (v0.z + v1.z) + (v2.z + v3.z);
        acc.w += (v0.w + v1.w) + (v2.w + v3.w);
    }
    for (; k < end; ++k) {
        const int s = csr_src[k];
        const float4 v = *reinterpret_cast<const float4*>(feat + (size_t)s * D + part * 4);
        acc.x += v.x; acc.y += v.y; acc.z += v.z; acc.w += v.w;
    }
    const float inv = 1.0f / fmaxf((float)(end - beg), 1.0f);
    acc.x *= inv; acc.y *= inv; acc.z *= inv; acc.w *= inv;
    *reinterpret_cast<float4*>(agg + (size_t)node * D + part * 4) = acc;
}

// ---------- dense: lane=out channel; weights in LDS (stride DIN+4);
//            node pairs, strip loop NOT unrolled (VGPR control) ----------

template <int DIN, bool POOL, int STRIP>
__launch_bounds__(256, 4)
__global__ void dense_kernel(const float* __restrict__ agg,
                             const float* __restrict__ xin,
                             const float* __restrict__ Wl,
                             const float* __restrict__ Wr,
                             const float* __restrict__ bias,
                             float* __restrict__ hout,
                             const int* __restrict__ batch,
                             float* __restrict__ pool_sum,
                             int N) {
    constexpr int PAD = DIN + 4;          // 16B-aligned rows; PAD/4 odd -> spread banks
    constexpr int NC4 = DIN / 4;
    __shared__ float wls[64 * PAD];
    __shared__ float wrs[64 * PAD];
    const int tid = threadIdx.x;
    for (int i = tid; i < 64 * DIN; i += 256) {
        const int o = i / DIN, c = i % DIN;
        wls[o * PAD + c] = Wl[i];
        wrs[o * PAD + c] = Wr[i];
    }
    __syncthreads();
    const int lane = tid & 63;
    const int wave = tid >> 6;
    const float* wlp = wls + lane * PAD;
    const float* wrp = wrs + lane * PAD;
    const float b = bias[lane];
    const int nodeBeg = (blockIdx.x * 4 + wave) * STRIP;
    float accg = 0.0f;
    int gcur = -1;
#pragma unroll 1
    for (int i = 0; i < STRIP; i += 2) {
        const int n0 = nodeBeg + i;
        const int n1 = n0 + 1;
        if (n0 >= N) break;                              // wave-uniform
        const bool has1 = (n1 < N);
        const int n1c = has1 ? n1 : n0;
        const float* a0 = agg + (size_t)n0 * DIN;
        const float* x0 = xin + (size_t)n0 * DIN;
        const float* a1 = agg + (size_t)n1c * DIN;
        const float* x1 = xin + (size_t)n1c * DIN;
        float acc0 = b, acc1 = b;
#pragma unroll
        for (int c4 = 0; c4 < NC4; ++c4) {
            const float4 wlv = *reinterpret_cast<const float4*>(wlp + c4 * 4);
            const float4 wrv = *reinterpret_cast<const float4*>(wrp + c4 * 4);
            const float4 av0 = *reinterpret_cast<const float4*>(a0 + c4 * 4);
            const float4 xv0 = *reinterpret_cast<const float4*>(x0 + c4 * 4);
            const float4 av1 = *reinterpret_cast<const float4*>(a1 + c4 * 4);
            const float4 xv1 = *reinterpret_cast<const float4*>(x1 + c4 * 4);
            acc0 = fmaf(av0.x, wlv.x, acc0);
            acc1 = fmaf(av1.x, wlv.x, acc1);
            acc0 = fmaf(av0.y, wlv.y, acc0);
            acc1 = fmaf(av1.y, wlv.y, acc1);
            acc0 = fmaf(av0.z, wlv.z, acc0);
            acc1 = fmaf(av1.z, wlv.z, acc1);
            acc0 = fmaf(av0.w, wlv.w, acc0);
            acc1 = fmaf(av1.w, wlv.w, acc1);
            acc0 = fmaf(xv0.x, wrv.x, acc0);
            acc1 = fmaf(xv1.x, wrv.x, acc1);
            acc0 = fmaf(xv0.y, wrv.y, acc0);
            acc1 = fmaf(xv1.y, wrv.y, acc1);
            acc0 = fmaf(xv0.z, wrv.z, acc0);
            acc1 = fmaf(xv1.z, wrv.z, acc1);
            acc0 = fmaf(xv0.w, wrv.w, acc0);
            acc1 = fmaf(xv1.w, wrv.w, acc1);
        }
        acc0 = fmaxf(acc0, 0.0f);
        acc1 = fmaxf(acc1, 0.0f);
        if (POOL) {
            const int g0 = batch[n0];                    // wave-uniform, sorted
            if (g0 != gcur) {
                if (gcur >= 0) atomicAdd(&pool_sum[(size_t)gcur * 64 + lane], accg);
                gcur = g0; accg = 0.0f;
            }
            accg += acc0;
            if (has1) {
                const int g1 = batch[n1];
                if (g1 != gcur) {
                    atomicAdd(&pool_sum[(size_t)gcur * 64 + lane], accg);
                    gcur = g1; accg = 0.0f;
                }
                accg += acc1;
            }
        } else {
            hout[(size_t)n0 * 64 + lane] = acc0;
            if (has1) hout[(size_t)n1 * 64 + lane] = acc1;
        }
    }
    if (POOL && gcur >= 0) atomicAdd(&pool_sum[(size_t)gcur * 64 + lane], accg);
}

// ---------- head ----------

__global__ void final_kernel(const float* __restrict__ pool_sum,
                             const int* __restrict__ cnt,
                             const float* __restrict__ W_lin,
                             const float* __restrict__ b_lin,
                             float* __restrict__ out, int G) {
    int t = blockIdx.x * blockDim.x + threadIdx.x;
    if (t >= G * 2) return;
    int g = t >> 1, o = t & 1;
    float inv = 1.0f / fmaxf((float)cnt[g], 1.0f);
    float acc = b_lin[o];
#pragma unroll
    for (int c = 0; c < 64; ++c)
        acc = fmaf(pool_sum[(size_t)g * 64 + c] * inv, W_lin[o * 64 + c], acc);
    out[t] = acc;
}

extern "C" void kernel_launch(void* const* d_in, const int* in_sizes, int n_in,
                              void* d_out, int out_size, void* d_ws, size_t ws_size,
                              hipStream_t stream) {
    const float* x     = (const float*)d_in[0];
    const int*   ei    = (const int*)d_in[1];
    const int*   batch = (const int*)d_in[2];
    const float* W1_l  = (const float*)d_in[3];
    const float* b1    = (const float*)d_in[4];
    const float* W1_r  = (const float*)d_in[5];
    const float* W2_l  = (const float*)d_in[6];
    const float* b2    = (const float*)d_in[7];
    const float* W2_r  = (const float*)d_in[8];
    const float* W_lin = (const float*)d_in[9];
    const float* b_lin = (const float*)d_in[10];

    const int N = in_sizes[0] / 32;
    const int E = in_sizes[1] / 2;
    const int G = out_size / 2;
    const int* src = ei;
    const int* dst = ei + E;
    const int NB = (N + BNODES - 1) >> BSHIFT;   // 196 for N=200000

    char* p = (char*)d_ws;
    auto carve = [&](size_t bytes) -> void* {
        void* r = (void*)p;
        p += (bytes + (WS_ALIGN - 1)) / WS_ALIGN * WS_ALIGN;
        return r;
    };
    int*      bucketCount  = (int*)carve(256 * 4);
    int*      bucketBase   = (int*)carve(257 * 4);
    int*      bucketCursor = (int*)carve(256 * 4);
    unsigned* bucketData   = (unsigned*)carve((size_t)E * 4);
    int*      offsets      = (int*)carve((size_t)(N + 1) * 4);
    int*      csr_src      = (int*)carve((size_t)E * 4);
    float*    agg          = (float*)carve((size_t)N * 64 * 4);
    float*    h1           = (float*)carve((size_t)N * 64 * 4);
    float*    pool         = (float*)carve((size_t)G * 64 * 4);
    int*      cnt          = (int*)carve((size_t)G * 4);
    float*    out          = (float*)d_out;

    hipMemsetAsync(bucketCount, 0, 256 * 4, stream);
    hipMemsetAsync(pool, 0, (size_t)G * 64 * 4, stream);
    hipMemsetAsync(cnt, 0, (size_t)G * 4, stream);

    const int TB = 256;
    cnt_kernel<<<(N + TB - 1) / TB, TB, 0, stream>>>(batch, cnt, N);
    bucket_hist_kernel<<<1024, TB, 0, stream>>>(dst, bucketCount, E);
    bucket_scan_kernel<<<1, TB, 0, stream>>>(bucketCount, bucketBase, bucketCursor, NB, E);
    bucket_scatter_kernel<<<(E + EPB - 1) / EPB, TB, 0, stream>>>(src, dst, bucketCursor,
                                                                  bucketData, E, NB);
    csr_build_kernel<<<NB, TB, 0, stream>>>(bucketData, bucketBase, offsets, csr_src, N, E, NB);

    // layer 1: aggregate x (D=32), dense 32->64 + relu -> h1
    agg_kernel<32><<<((size_t)N * 8 + TB - 1) / TB, TB, 0, stream>>>(x, csr_src, offsets, agg, N);
    dense_kernel<32, false, 16><<<(N + 63) / 64, TB, 0, stream>>>(agg, x, W1_l, W1_r, b1, h1,
                                                                  nullptr, nullptr, N);

    // layer 2: aggregate h1 (D=64), dense 64->64 + relu fused with pooling
    agg_kernel<64><<<((size_t)N * 16 + TB - 1) / TB, TB, 0, stream>>>(h1, csr_src, offsets, agg, N);
    dense_kernel<64, true, 16><<<(N + 63) / 64, TB, 0, stream>>>(agg, h1, W2_l, W2_r, b2, nullptr,
                                                                 batch, pool, N);

    final_kernel<<<(G * 2 + TB - 1) / TB, TB, 0, stream>>>(pool, cnt, W_lin, b_lin, out, G);
}

// Round 8
// 764.046 us; speedup vs baseline: 4.9352x; 4.9352x over previous
//
#include <hip/hip_runtime.h>
#include <hip/hip_bf16.h>

// JetGNN: 2-layer SAGEConv(mean) + ReLU + global_mean_pool + Linear(64->2)
// R1: hierarchical scan. R2: bucketed counting-sort CSR build.
// R3: run-flush pool (50MB->4MB atomics). R4: agg x4 unroll WIN (~95us).
// R5/R6: LDS weights (stride 68, conflict-free); VGPR 204 from full unroll
//     of STRIP loop hoisting ~48 float4 loads (264us, occ 10.8%).
// R7: unroll-1 + __launch_bounds__(256,4) -> allocator forced to 128 VGPR,
//     SPILLED 10.8GB to scratch, 3262us. NEVER pair min-waves bound with a
//     rolled loop here.
// R8: R6 + '#pragma unroll 1' ONLY (no min-waves bound). Rolled live set
//     ~40 VGPR -> allocator should land ~100, no spill, occ ~25-40%.

#define WS_ALIGN 64
#define EPB 4096          // edges per block in bucket_scatter (256 thr x 16)
#define BSHIFT 10         // 1024 nodes per bucket
#define BNODES 1024

// ---------- pooling counts ----------

__global__ void cnt_kernel(const int* __restrict__ batch, int* __restrict__ cnt, int N) {
    int i = blockIdx.x * blockDim.x + threadIdx.x;
    if (i < N) atomicAdd(&cnt[batch[i]], 1);
}

// ---------- bucketed CSR construction ----------

__global__ __launch_bounds__(256) void bucket_hist_kernel(const int* __restrict__ dst,
                                                          int* __restrict__ bucketCount, int E) {
    __shared__ int hist[256];
    const int t = threadIdx.x;
    hist[t] = 0;
    __syncthreads();
    for (int e = blockIdx.x * blockDim.x + t; e < E; e += gridDim.x * blockDim.x)
        atomicAdd(&hist[dst[e] >> BSHIFT], 1);
    __syncthreads();
    if (hist[t] > 0) atomicAdd(&bucketCount[t], hist[t]);
}

__global__ __launch_bounds__(256) void bucket_scan_kernel(const int* __restrict__ bucketCount,
                                                          int* __restrict__ bucketBase,
                                                          int* __restrict__ bucketCursor,
                                                          int NB, int E) {
    __shared__ int s[256];
    const int t = threadIdx.x;
    int v = (t < NB) ? bucketCount[t] : 0;
    s[t] = v;
    __syncthreads();
    for (int off = 1; off < 256; off <<= 1) {
        int u = (t >= off) ? s[t - off] : 0;
        __syncthreads();
        s[t] += u;
        __syncthreads();
    }
    int excl = s[t] - v;
    if (t < NB) { bucketBase[t] = excl; bucketCursor[t] = excl; }
    if (t == 0) bucketBase[NB] = E;
}

__global__ __launch_bounds__(256) void bucket_scatter_kernel(const int* __restrict__ src,
                                                             const int* __restrict__ dst,
                                                             int* __restrict__ bucketCursor,
                                                             unsigned* __restrict__ bucketData,
                                                             int E, int NB) {
    __shared__ int hist[256];
    __shared__ int cur[256];
    const int t = threadIdx.x;
    hist[t] = 0;
    __syncthreads();
    const int eBase = blockIdx.x * EPB + t;
    int s[16], b[16], dl[16];
#pragma unroll
    for (int j = 0; j < 16; ++j) {
        int e = eBase + j * 256;
        if (e < E) {
            int d = dst[e];
            s[j]  = src[e];
            b[j]  = d >> BSHIFT;
            dl[j] = d & (BNODES - 1);
            atomicAdd(&hist[b[j]], 1);
        } else {
            b[j] = -1;
        }
    }
    __syncthreads();
    if (t < NB && hist[t] > 0) cur[t] = atomicAdd(&bucketCursor[t], hist[t]);
    __syncthreads();
#pragma unroll
    for (int j = 0; j < 16; ++j) {
        if (b[j] >= 0) {
            int pos = atomicAdd(&cur[b[j]], 1);
            bucketData[pos] = ((unsigned)s[j] << BSHIFT) | (unsigned)dl[j];
        }
    }
}

__global__ __launch_bounds__(256) void csr_build_kernel(const unsigned* __restrict__ bucketData,
                                                        const int* __restrict__ bucketBase,
                                                        int* __restrict__ offsets,
                                                        int* __restrict__ csr_src,
                                                        int N, int E, int NB) {
    __shared__ int cnt[BNODES];
    __shared__ int sscan[256];
    __shared__ int cur[BNODES];
    const int t   = threadIdx.x;
    const int bkt = blockIdx.x;
    const int beg = bucketBase[bkt];
    const int end = bucketBase[bkt + 1];
    for (int i = t; i < BNODES; i += 256) cnt[i] = 0;
    __syncthreads();
    for (int k = beg + t; k < end; k += 256)
        atomicAdd(&cnt[bucketData[k] & (BNODES - 1)], 1);
    __syncthreads();
    int local[4];
    int sum = 0;
#pragma unroll
    for (int j = 0; j < 4; ++j) { local[j] = sum; sum += cnt[t * 4 + j]; }
    sscan[t] = sum;
    __syncthreads();
    for (int off = 1; off < 256; off <<= 1) {
        int v = (t >= off) ? sscan[t - off] : 0;
        __syncthreads();
        sscan[t] += v;
        __syncthreads();
    }
    int base = (t > 0) ? sscan[t - 1] : 0;
#pragma unroll
    for (int j = 0; j < 4; ++j) cur[t * 4 + j] = base + local[j];
    __syncthreads();
    for (int i = t; i < BNODES; i += 256) {
        int node = (bkt << BSHIFT) + i;
        if (node <= N) offsets[node] = beg + cur[i];
    }
    if (bkt == NB - 1 && t == 0 && (NB << BSHIFT) == N) offsets[N] = E;
    __syncthreads();
    for (int k = beg + t; k < end; k += 256) {
        unsigned v = bucketData[k];
        int d   = (int)(v & (BNODES - 1));
        int pos = beg + atomicAdd(&cur[d], 1);
        csr_src[pos] = (int)(v >> BSHIFT);
    }
}

// ---------- mean aggregation (node-parallel, D/4 threads per node) ----------
// R4: neighbor loop unrolled x4 -> 4 independent gathers in flight (WIN ~95us).

template <int D>
__global__ void agg_kernel(const float* __restrict__ feat,
                           const int* __restrict__ csr_src,
                           const int* __restrict__ offsets,
                           float* __restrict__ agg, int N) {
    constexpr int TPN = D / 4;
    int tid  = blockIdx.x * blockDim.x + threadIdx.x;
    int node = tid / TPN;
    int part = tid % TPN;
    if (node >= N) return;
    const int beg = offsets[node];
    const int end = offsets[node + 1];
    float4 acc = make_float4(0.f, 0.f, 0.f, 0.f);
    int k = beg;
    for (; k + 4 <= end; k += 4) {
        const int s0 = csr_src[k + 0];
        const int s1 = csr_src[k + 1];
        const int s2 = csr_src[k + 2];
        const int s3 = csr_src[k + 3];
        const float4 v0 = *reinterpret_cast<const float4*>(feat + (size_t)s0 * D + part * 4);
        const float4 v1 = *reinterpret_cast<const float4*>(feat + (size_t)s1 * D + part * 4);
        const float4 v2 = *reinterpret_cast<const float4*>(feat + (size_t)s2 * D + part * 4);
        const float4 v3 = *reinterpret_cast<const float4*>(feat + (size_t)s3 * D + part * 4);
        acc.x += (v0.x + v1.x) + (v2.x + v3.x);
        acc.y += (v0.y + v1.y) + (v2.y + v3.y);
        acc.z += (v0.z + v1.z) + (v2.z + v3.z);
        acc.w += (v0.w + v1.w) + (v2.w + v3.w);
    }
    for (; k < end; ++k) {
        const int s = csr_src[k];
        const float4 v = *reinterpret_cast<const float4*>(feat + (size_t)s * D + part * 4);
        acc.x += v.x; acc.y += v.y; acc.z += v.z; acc.w += v.w;
    }
    const float inv = 1.0f / fmaxf((float)(end - beg), 1.0f);
    acc.x *= inv; acc.y *= inv; acc.z *= inv; acc.w *= inv;
    *reinterpret_cast<float4*>(agg + (size_t)node * D + part * 4) = acc;
}

// ---------- dense: lane=out channel; weights in LDS (stride DIN+4);
//            node pairs; strip loop rolled via unroll 1 (VGPR control);
//            NO min-waves launch bound (R7 spill lesson) ----------

template <int DIN, bool POOL, int STRIP>
__launch_bounds__(256)
__global__ void dense_kernel(const float* __restrict__ agg,
                             const float* __restrict__ xin,
                             const float* __restrict__ Wl,
                             const float* __restrict__ Wr,
                             const float* __restrict__ bias,
                             float* __restrict__ hout,
                             const int* __restrict__ batch,
                             float* __restrict__ pool_sum,
                             int N) {
    constexpr int PAD = DIN + 4;          // 16B-aligned rows; PAD/4 odd -> spread banks
    constexpr int NC4 = DIN / 4;
    __shared__ float wls[64 * PAD];
    __shared__ float wrs[64 * PAD];
    const int tid = threadIdx.x;
    for (int i = tid; i < 64 * DIN; i += 256) {
        const int o = i / DIN, c = i % DIN;
        wls[o * PAD + c] = Wl[i];
        wrs[o * PAD + c] = Wr[i];
    }
    __syncthreads();
    const int lane = tid & 63;
    const int wave = tid >> 6;
    const float* wlp = wls + lane * PAD;
    const float* wrp = wrs + lane * PAD;
    const float b = bias[lane];
    const int nodeBeg = (blockIdx.x * 4 + wave) * STRIP;
    float accg = 0.0f;
    int gcur = -1;
#pragma unroll 1
    for (int i = 0; i < STRIP; i += 2) {
        const int n0 = nodeBeg + i;
        const int n1 = n0 + 1;
        if (n0 >= N) break;                              // wave-uniform
        const bool has1 = (n1 < N);
        const int n1c = has1 ? n1 : n0;
        const float* a0 = agg + (size_t)n0 * DIN;
        const float* x0 = xin + (size_t)n0 * DIN;
        const float* a1 = agg + (size_t)n1c * DIN;
        const float* x1 = xin + (size_t)n1c * DIN;
        float acc0 = b, acc1 = b;
#pragma unroll
        for (int c4 = 0; c4 < NC4; ++c4) {
            const float4 wlv = *reinterpret_cast<const float4*>(wlp + c4 * 4);
            const float4 wrv = *reinterpret_cast<const float4*>(wrp + c4 * 4);
            const float4 av0 = *reinterpret_cast<const float4*>(a0 + c4 * 4);
            const float4 xv0 = *reinterpret_cast<const float4*>(x0 + c4 * 4);
            const float4 av1 = *reinterpret_cast<const float4*>(a1 + c4 * 4);
            const float4 xv1 = *reinterpret_cast<const float4*>(x1 + c4 * 4);
            acc0 = fmaf(av0.x, wlv.x, acc0);
            acc1 = fmaf(av1.x, wlv.x, acc1);
            acc0 = fmaf(av0.y, wlv.y, acc0);
            acc1 = fmaf(av1.y, wlv.y, acc1);
            acc0 = fmaf(av0.z, wlv.z, acc0);
            acc1 = fmaf(av1.z, wlv.z, acc1);
            acc0 = fmaf(av0.w, wlv.w, acc0);
            acc1 = fmaf(av1.w, wlv.w, acc1);
            acc0 = fmaf(xv0.x, wrv.x, acc0);
            acc1 = fmaf(xv1.x, wrv.x, acc1);
            acc0 = fmaf(xv0.y, wrv.y, acc0);
            acc1 = fmaf(xv1.y, wrv.y, acc1);
            acc0 = fmaf(xv0.z, wrv.z, acc0);
            acc1 = fmaf(xv1.z, wrv.z, acc1);
            acc0 = fmaf(xv0.w, wrv.w, acc0);
            acc1 = fmaf(xv1.w, wrv.w, acc1);
        }
        acc0 = fmaxf(acc0, 0.0f);
        acc1 = fmaxf(acc1, 0.0f);
        if (POOL) {
            const int g0 = batch[n0];                    // wave-uniform, sorted
            if (g0 != gcur) {
                if (gcur >= 0) atomicAdd(&pool_sum[(size_t)gcur * 64 + lane], accg);
                gcur = g0; accg = 0.0f;
            }
            accg += acc0;
            if (has1) {
                const int g1 = batch[n1];
                if (g1 != gcur) {
                    atomicAdd(&pool_sum[(size_t)gcur * 64 + lane], accg);
                    gcur = g1; accg = 0.0f;
                }
                accg += acc1;
            }
        } else {
            hout[(size_t)n0 * 64 + lane] = acc0;
            if (has1) hout[(size_t)n1 * 64 + lane] = acc1;
        }
    }
    if (POOL && gcur >= 0) atomicAdd(&pool_sum[(size_t)gcur * 64 + lane], accg);
}

// ---------- head ----------

__global__ void final_kernel(const float* __restrict__ pool_sum,
                             const int* __restrict__ cnt,
                             const float* __restrict__ W_lin,
                             const float* __restrict__ b_lin,
                             float* __restrict__ out, int G) {
    int t = blockIdx.x * blockDim.x + threadIdx.x;
    if (t >= G * 2) return;
    int g = t >> 1, o = t & 1;
    float inv = 1.0f / fmaxf((float)cnt[g], 1.0f);
    float acc = b_lin[o];
#pragma unroll
    for (int c = 0; c < 64; ++c)
        acc = fmaf(pool_sum[(size_t)g * 64 + c] * inv, W_lin[o * 64 + c], acc);
    out[t] = acc;
}

extern "C" void kernel_launch(void* const* d_in, const int* in_sizes, int n_in,
                              void* d_out, int out_size, void* d_ws, size_t ws_size,
                              hipStream_t stream) {
    const float* x     = (const float*)d_in[0];
    const int*   ei    = (const int*)d_in[1];
    const int*   batch = (const int*)d_in[2];
    const float* W1_l  = (const float*)d_in[3];
    const float* b1    = (const float*)d_in[4];
    const float* W1_r  = (const float*)d_in[5];
    const float* W2_l  = (const float*)d_in[6];
    const float* b2    = (const float*)d_in[7];
    const float* W2_r  = (const float*)d_in[8];
    const float* W_lin = (const float*)d_in[9];
    const float* b_lin = (const float*)d_in[10];

    const int N = in_sizes[0] / 32;
    const int E = in_sizes[1] / 2;
    const int G = out_size / 2;
    const int* src = ei;
    const int* dst = ei + E;
    const int NB = (N + BNODES - 1) >> BSHIFT;   // 196 for N=200000

    char* p = (char*)d_ws;
    auto carve = [&](size_t bytes) -> void* {
        void* r = (void*)p;
        p += (bytes + (WS_ALIGN - 1)) / WS_ALIGN * WS_ALIGN;
        return r;
    };
    int*      bucketCount  = (int*)carve(256 * 4);
    int*      bucketBase   = (int*)carve(257 * 4);
    int*      bucketCursor = (int*)carve(256 * 4);
    unsigned* bucketData   = (unsigned*)carve((size_t)E * 4);
    int*      offsets      = (int*)carve((size_t)(N + 1) * 4);
    int*      csr_src      = (int*)carve((size_t)E * 4);
    float*    agg          = (float*)carve((size_t)N * 64 * 4);
    float*    h1           = (float*)carve((size_t)N * 64 * 4);
    float*    pool         = (float*)carve((size_t)G * 64 * 4);
    int*      cnt          = (int*)carve((size_t)G * 4);
    float*    out          = (float*)d_out;

    hipMemsetAsync(bucketCount, 0, 256 * 4, stream);
    hipMemsetAsync(pool, 0, (size_t)G * 64 * 4, stream);
    hipMemsetAsync(cnt, 0, (size_t)G * 4, stream);

    const int TB = 256;
    cnt_kernel<<<(N + TB - 1) / TB, TB, 0, stream>>>(batch, cnt, N);
    bucket_hist_kernel<<<1024, TB, 0, stream>>>(dst, bucketCount, E);
    bucket_scan_kernel<<<1, TB, 0, stream>>>(bucketCount, bucketBase, bucketCursor, NB, E);
    bucket_scatter_kernel<<<(E + EPB - 1) / EPB, TB, 0, stream>>>(src, dst, bucketCursor,
                                                                  bucketData, E, NB);
    csr_build_kernel<<<NB, TB, 0, stream>>>(bucketData, bucketBase, offsets, csr_src, N, E, NB);

    // layer 1: aggregate x (D=32), dense 32->64 + relu -> h1
    agg_kernel<32><<<((size_t)N * 8 + TB - 1) / TB, TB, 0, stream>>>(x, csr_src, offsets, agg, N);
    dense_kernel<32, false, 16><<<(N + 63) / 64, TB, 0, stream>>>(agg, x, W1_l, W1_r, b1, h1,
                                                                  nullptr, nullptr, N);

    // layer 2: aggregate h1 (D=64), dense 64->64 + relu fused with pooling
    agg_kernel<64><<<((size_t)N * 16 + TB - 1) / TB, TB, 0, stream>>>(h1, csr_src, offsets, agg, N);
    dense_kernel<64, true, 16><<<(N + 63) / 64, TB, 0, stream>>>(agg, h1, W2_l, W2_r, b2, nullptr,
                                                                 batch, pool, N);

    final_kernel<<<(G * 2 + TB - 1) / TB, TB, 0, stream>>>(pool, cnt, W_lin, b_lin, out, G);
}

// Round 9
// 587.987 us; speedup vs baseline: 6.4130x; 1.2994x over previous
//
#include <hip/hip_runtime.h>
#include <hip/hip_bf16.h>

// JetGNN: 2-layer SAGEConv(mean) + ReLU + global_mean_pool + Linear(64->2)
// R1: hierarchical scan. R2: bucketed counting-sort CSR build.
// R3: run-flush pool (50MB->4MB atomics). R4: agg x4 unroll WIN (~95us).
// R5-R8: the "wave-uniform strip" dense structure is unfixable: compiler
//     either hoists ~48 global float4s (VGPR 204, occ 11%, 264us) or,
//     when forced (launch_bounds min-waves), spills 10.8GB (3262us).
//     '#pragma unroll 1' is ignored.
// R9: dense rewritten as classic LDS-tiled GEMM [64 nodes x 64 outs]/block,
//     4x4 register tile/thread, bit-permuted LDS rows (odd f4 stride ->
//     conflict-free b128), K staged in 64-wide phases (50KB LDS max).

#define WS_ALIGN 64
#define EPB 4096          // edges per block in bucket_scatter (256 thr x 16)
#define BSHIFT 10         // 1024 nodes per bucket
#define BNODES 1024

// ---------- pooling counts ----------

__global__ void cnt_kernel(const int* __restrict__ batch, int* __restrict__ cnt, int N) {
    int i = blockIdx.x * blockDim.x + threadIdx.x;
    if (i < N) atomicAdd(&cnt[batch[i]], 1);
}

// ---------- bucketed CSR construction ----------

__global__ __launch_bounds__(256) void bucket_hist_kernel(const int* __restrict__ dst,
                                                          int* __restrict__ bucketCount, int E) {
    __shared__ int hist[256];
    const int t = threadIdx.x;
    hist[t] = 0;
    __syncthreads();
    for (int e = blockIdx.x * blockDim.x + t; e < E; e += gridDim.x * blockDim.x)
        atomicAdd(&hist[dst[e] >> BSHIFT], 1);
    __syncthreads();
    if (hist[t] > 0) atomicAdd(&bucketCount[t], hist[t]);
}

__global__ __launch_bounds__(256) void bucket_scan_kernel(const int* __restrict__ bucketCount,
                                                          int* __restrict__ bucketBase,
                                                          int* __restrict__ bucketCursor,
                                                          int NB, int E) {
    __shared__ int s[256];
    const int t = threadIdx.x;
    int v = (t < NB) ? bucketCount[t] : 0;
    s[t] = v;
    __syncthreads();
    for (int off = 1; off < 256; off <<= 1) {
        int u = (t >= off) ? s[t - off] : 0;
        __syncthreads();
        s[t] += u;
        __syncthreads();
    }
    int excl = s[t] - v;
    if (t < NB) { bucketBase[t] = excl; bucketCursor[t] = excl; }
    if (t == 0) bucketBase[NB] = E;
}

__global__ __launch_bounds__(256) void bucket_scatter_kernel(const int* __restrict__ src,
                                                             const int* __restrict__ dst,
                                                             int* __restrict__ bucketCursor,
                                                             unsigned* __restrict__ bucketData,
                                                             int E, int NB) {
    __shared__ int hist[256];
    __shared__ int cur[256];
    const int t = threadIdx.x;
    hist[t] = 0;
    __syncthreads();
    const int eBase = blockIdx.x * EPB + t;
    int s[16], b[16], dl[16];
#pragma unroll
    for (int j = 0; j < 16; ++j) {
        int e = eBase + j * 256;
        if (e < E) {
            int d = dst[e];
            s[j]  = src[e];
            b[j]  = d >> BSHIFT;
            dl[j] = d & (BNODES - 1);
            atomicAdd(&hist[b[j]], 1);
        } else {
            b[j] = -1;
        }
    }
    __syncthreads();
    if (t < NB && hist[t] > 0) cur[t] = atomicAdd(&bucketCursor[t], hist[t]);
    __syncthreads();
#pragma unroll
    for (int j = 0; j < 16; ++j) {
        if (b[j] >= 0) {
            int pos = atomicAdd(&cur[b[j]], 1);
            bucketData[pos] = ((unsigned)s[j] << BSHIFT) | (unsigned)dl[j];
        }
    }
}

__global__ __launch_bounds__(256) void csr_build_kernel(const unsigned* __restrict__ bucketData,
                                                        const int* __restrict__ bucketBase,
                                                        int* __restrict__ offsets,
                                                        int* __restrict__ csr_src,
                                                        int N, int E, int NB) {
    __shared__ int cnt[BNODES];
    __shared__ int sscan[256];
    __shared__ int cur[BNODES];
    const int t   = threadIdx.x;
    const int bkt = blockIdx.x;
    const int beg = bucketBase[bkt];
    const int end = bucketBase[bkt + 1];
    for (int i = t; i < BNODES; i += 256) cnt[i] = 0;
    __syncthreads();
    for (int k = beg + t; k < end; k += 256)
        atomicAdd(&cnt[bucketData[k] & (BNODES - 1)], 1);
    __syncthreads();
    int local[4];
    int sum = 0;
#pragma unroll
    for (int j = 0; j < 4; ++j) { local[j] = sum; sum += cnt[t * 4 + j]; }
    sscan[t] = sum;
    __syncthreads();
    for (int off = 1; off < 256; off <<= 1) {
        int v = (t >= off) ? sscan[t - off] : 0;
        __syncthreads();
        sscan[t] += v;
        __syncthreads();
    }
    int base = (t > 0) ? sscan[t - 1] : 0;
#pragma unroll
    for (int j = 0; j < 4; ++j) cur[t * 4 + j] = base + local[j];
    __syncthreads();
    for (int i = t; i < BNODES; i += 256) {
        int node = (bkt << BSHIFT) + i;
        if (node <= N) offsets[node] = beg + cur[i];
    }
    if (bkt == NB - 1 && t == 0 && (NB << BSHIFT) == N) offsets[N] = E;
    __syncthreads();
    for (int k = beg + t; k < end; k += 256) {
        unsigned v = bucketData[k];
        int d   = (int)(v & (BNODES - 1));
        int pos = beg + atomicAdd(&cur[d], 1);
        csr_src[pos] = (int)(v >> BSHIFT);
    }
}

// ---------- mean aggregation (node-parallel, D/4 threads per node) ----------
// R4: neighbor loop unrolled x4 -> 4 independent gathers in flight (WIN ~95us).

template <int D>
__global__ void agg_kernel(const float* __restrict__ feat,
                           const int* __restrict__ csr_src,
                           const int* __restrict__ offsets,
                           float* __restrict__ agg, int N) {
    constexpr int TPN = D / 4;
    int tid  = blockIdx.x * blockDim.x + threadIdx.x;
    int node = tid / TPN;
    int part = tid % TPN;
    if (node >= N) return;
    const int beg = offsets[node];
    const int end = offsets[node + 1];
    float4 acc = make_float4(0.f, 0.f, 0.f, 0.f);
    int k = beg;
    for (; k + 4 <= end; k += 4) {
        const int s0 = csr_src[k + 0];
        const int s1 = csr_src[k + 1];
        const int s2 = csr_src[k + 2];
        const int s3 = csr_src[k + 3];
        const float4 v0 = *reinterpret_cast<const float4*>(feat + (size_t)s0 * D + part * 4);
        const float4 v1 = *reinterpret_cast<const float4*>(feat + (size_t)s1 * D + part * 4);
        const float4 v2 = *reinterpret_cast<const float4*>(feat + (size_t)s2 * D + part * 4);
        const float4 v3 = *reinterpret_cast<const float4*>(feat + (size_t)s3 * D + part * 4);
        acc.x += (v0.x + v1.x) + (v2.x + v3.x);
        acc.y += (v0.y + v1.y) + (v2.y + v3.y);
        acc.z += (v0.z + v1.z) + (v2.z + v3.z);
        acc.w += (v0.w + v1.w) + (v2.w + v3.w);
    }
    for (; k < end; ++k) {
        const int s = csr_src[k];
        const float4 v = *reinterpret_cast<const float4*>(feat + (size_t)s * D + part * 4);
        acc.x += v.x; acc.y += v.y; acc.z += v.z; acc.w += v.w;
    }
    const float inv = 1.0f / fmaxf((float)(end - beg), 1.0f);
    acc.x *= inv; acc.y *= inv; acc.z *= inv; acc.w *= inv;
    *reinterpret_cast<float4*>(agg + (size_t)node * D + part * 4) = acc;
}

// ---------- dense as LDS-tiled GEMM ----------
// C[64 nodes][64 outs] per block = [agg|x] @ [Wl|Wr]^T, K = 2*DIN.
// Thread (ti,tj) = (tid>>4, tid&15) computes 4x4 tile: nodes ti*4+i,
// outs tj*4+j. LDS rows bit-permuted: row' = ((r&3)<<4)|(r>>2) so compute
// reads stride an ODD number of float4s -> all 8 bank-quads covered.
// K staged in 64-wide phases so layer2 (K=128) LDS = 33.8+17.4 = 50KB.

template <int DIN, bool POOL>
__launch_bounds__(256)
__global__ void gemm_dense_kernel(const float* __restrict__ agg,
                                  const float* __restrict__ xin,
                                  const float* __restrict__ Wl,
                                  const float* __restrict__ Wr,
                                  const float* __restrict__ bias,
                                  float* __restrict__ hout,
                                  const int* __restrict__ batch,
                                  float* __restrict__ pool_sum,
                                  int N) {
    constexpr int K   = 2 * DIN;    // 64 or 128
    constexpr int K4  = K / 4;      // 16 or 32
    constexpr int WS4 = K4 + 1;     // w_s row stride (float4), odd
    constexpr int AS4 = 17;         // a_s row stride (float4), odd
    constexpr int D4  = DIN / 4;
    constexpr int NPH = K / 64;     // k-phases
    __shared__ float4 w_s[64 * WS4];
    __shared__ float4 a_s[64 * AS4];
    const int tid = threadIdx.x;
    const int ti = tid >> 4;        // node group 0..15
    const int tj = tid & 15;        // out group 0..15
    const int nodeBase = blockIdx.x * 64;

    // stage weights: w_s[perm(o)][k] = [Wl[o] | Wr[o]] (o-major global: coalesced)
    for (int g = tid; g < 64 * K4; g += 256) {
        const int o  = g / K4;
        const int c4 = g % K4;
        const float4 v = (c4 < D4)
            ? *reinterpret_cast<const float4*>(Wl + (size_t)o * DIN + c4 * 4)
            : *reinterpret_cast<const float4*>(Wr + (size_t)o * DIN + (c4 - D4) * 4);
        const int oP = ((o & 3) << 4) | (o >> 2);
        w_s[oP * WS4 + c4] = v;
    }

    const float4 bv = *reinterpret_cast<const float4*>(bias + tj * 4);
    float acc[4][4];
#pragma unroll
    for (int i = 0; i < 4; ++i) {
        acc[i][0] = bv.x; acc[i][1] = bv.y; acc[i][2] = bv.z; acc[i][3] = bv.w;
    }

    for (int p = 0; p < NPH; ++p) {
        __syncthreads();   // p==0: w_s ready; p>0: previous-phase readers done
        // stage features for k in [p*64, p*64+64): a_s[perm(node)][kk]
        for (int g = tid; g < 64 * 16; g += 256) {
            const int node = g >> 4;
            const int k4   = g & 15;
            const int gk4  = p * 16 + k4;
            const int n = min(nodeBase + node, N - 1);
            const float4 v = (gk4 < D4)
                ? *reinterpret_cast<const float4*>(agg + (size_t)n * DIN + gk4 * 4)
                : *reinterpret_cast<const float4*>(xin + (size_t)n * DIN + (gk4 - D4) * 4);
            const int nP = ((node & 3) << 4) | (node >> 2);
            a_s[nP * AS4 + k4] = v;
        }
        __syncthreads();
#pragma unroll
        for (int k4 = 0; k4 < 16; ++k4) {
            float4 av[4], wv[4];
#pragma unroll
            for (int i = 0; i < 4; ++i)
                av[i] = a_s[(ti + 16 * i) * AS4 + k4];     // perm(ti*4+i) = ti+16i
#pragma unroll
            for (int j = 0; j < 4; ++j)
                wv[j] = w_s[(tj + 16 * j) * WS4 + p * 16 + k4];
#pragma unroll
            for (int i = 0; i < 4; ++i)
#pragma unroll
                for (int j = 0; j < 4; ++j) {
                    acc[i][j] = fmaf(av[i].x, wv[j].x, acc[i][j]);
                    acc[i][j] = fmaf(av[i].y, wv[j].y, acc[i][j]);
                    acc[i][j] = fmaf(av[i].z, wv[j].z, acc[i][j]);
                    acc[i][j] = fmaf(av[i].w, wv[j].w, acc[i][j]);
                }
        }
    }

#pragma unroll
    for (int i = 0; i < 4; ++i)
#pragma unroll
        for (int j = 0; j < 4; ++j)
            acc[i][j] = fmaxf(acc[i][j], 0.0f);

    if (POOL) {
        float ag0 = 0.f, ag1 = 0.f, ag2 = 0.f, ag3 = 0.f;
        int gcur = -1;
#pragma unroll
        for (int i = 0; i < 4; ++i) {
            const int n = nodeBase + ti * 4 + i;
            if (n < N) {
                const int g = batch[n];      // sorted
                if (g != gcur) {
                    if (gcur >= 0) {
                        atomicAdd(&pool_sum[(size_t)gcur * 64 + tj * 4 + 0], ag0);
                        atomicAdd(&pool_sum[(size_t)gcur * 64 + tj * 4 + 1], ag1);
                        atomicAdd(&pool_sum[(size_t)gcur * 64 + tj * 4 + 2], ag2);
                        atomicAdd(&pool_sum[(size_t)gcur * 64 + tj * 4 + 3], ag3);
                    }
                    gcur = g; ag0 = ag1 = ag2 = ag3 = 0.f;
                }
                ag0 += acc[i][0]; ag1 += acc[i][1]; ag2 += acc[i][2]; ag3 += acc[i][3];
            }
        }
        if (gcur >= 0) {
            atomicAdd(&pool_sum[(size_t)gcur * 64 + tj * 4 + 0], ag0);
            atomicAdd(&pool_sum[(size_t)gcur * 64 + tj * 4 + 1], ag1);
            atomicAdd(&pool_sum[(size_t)gcur * 64 + tj * 4 + 2], ag2);
            atomicAdd(&pool_sum[(size_t)gcur * 64 + tj * 4 + 3], ag3);
        }
    } else {
#pragma unroll
        for (int i = 0; i < 4; ++i) {
            const int n = nodeBase + ti * 4 + i;
            if (n < N) {
                const float4 o4 = make_float4(acc[i][0], acc[i][1], acc[i][2], acc[i][3]);
                *reinterpret_cast<float4*>(hout + (size_t)n * 64 + tj * 4) = o4;
            }
        }
    }
}

// ---------- head ----------

__global__ void final_kernel(const float* __restrict__ pool_sum,
                             const int* __restrict__ cnt,
                             const float* __restrict__ W_lin,
                             const float* __restrict__ b_lin,
                             float* __restrict__ out, int G) {
    int t = blockIdx.x * blockDim.x + threadIdx.x;
    if (t >= G * 2) return;
    int g = t >> 1, o = t & 1;
    float inv = 1.0f / fmaxf((float)cnt[g], 1.0f);
    float acc = b_lin[o];
#pragma unroll
    for (int c = 0; c < 64; ++c)
        acc = fmaf(pool_sum[(size_t)g * 64 + c] * inv, W_lin[o * 64 + c], acc);
    out[t] = acc;
}

extern "C" void kernel_launch(void* const* d_in, const int* in_sizes, int n_in,
                              void* d_out, int out_size, void* d_ws, size_t ws_size,
                              hipStream_t stream) {
    const float* x     = (const float*)d_in[0];
    const int*   ei    = (const int*)d_in[1];
    const int*   batch = (const int*)d_in[2];
    const float* W1_l  = (const float*)d_in[3];
    const float* b1    = (const float*)d_in[4];
    const float* W1_r  = (const float*)d_in[5];
    const float* W2_l  = (const float*)d_in[6];
    const float* b2    = (const float*)d_in[7];
    const float* W2_r  = (const float*)d_in[8];
    const float* W_lin = (const float*)d_in[9];
    const float* b_lin = (const float*)d_in[10];

    const int N = in_sizes[0] / 32;
    const int E = in_sizes[1] / 2;
    const int G = out_size / 2;
    const int* src = ei;
    const int* dst = ei + E;
    const int NB = (N + BNODES - 1) >> BSHIFT;   // 196 for N=200000

    char* p = (char*)d_ws;
    auto carve = [&](size_t bytes) -> void* {
        void* r = (void*)p;
        p += (bytes + (WS_ALIGN - 1)) / WS_ALIGN * WS_ALIGN;
        return r;
    };
    int*      bucketCount  = (int*)carve(256 * 4);
    int*      bucketBase   = (int*)carve(257 * 4);
    int*      bucketCursor = (int*)carve(256 * 4);
    unsigned* bucketData   = (unsigned*)carve((size_t)E * 4);
    int*      offsets      = (int*)carve((size_t)(N + 1) * 4);
    int*      csr_src      = (int*)carve((size_t)E * 4);
    float*    agg          = (float*)carve((size_t)N * 64 * 4);
    float*    h1           = (float*)carve((size_t)N * 64 * 4);
    float*    pool         = (float*)carve((size_t)G * 64 * 4);
    int*      cnt          = (int*)carve((size_t)G * 4);
    float*    out          = (float*)d_out;

    hipMemsetAsync(bucketCount, 0, 256 * 4, stream);
    hipMemsetAsync(pool, 0, (size_t)G * 64 * 4, stream);
    hipMemsetAsync(cnt, 0, (size_t)G * 4, stream);

    const int TB = 256;
    cnt_kernel<<<(N + TB - 1) / TB, TB, 0, stream>>>(batch, cnt, N);
    bucket_hist_kernel<<<1024, TB, 0, stream>>>(dst, bucketCount, E);
    bucket_scan_kernel<<<1, TB, 0, stream>>>(bucketCount, bucketBase, bucketCursor, NB, E);
    bucket_scatter_kernel<<<(E + EPB - 1) / EPB, TB, 0, stream>>>(src, dst, bucketCursor,
                                                                  bucketData, E, NB);
    csr_build_kernel<<<NB, TB, 0, stream>>>(bucketData, bucketBase, offsets, csr_src, N, E, NB);

    // layer 1: aggregate x (D=32), GEMM-dense 32->64 + relu -> h1
    agg_kernel<32><<<((size_t)N * 8 + TB - 1) / TB, TB, 0, stream>>>(x, csr_src, offsets, agg, N);
    gemm_dense_kernel<32, false><<<(N + 63) / 64, TB, 0, stream>>>(agg, x, W1_l, W1_r, b1, h1,
                                                                   nullptr, nullptr, N);

    // layer 2: aggregate h1 (D=64), GEMM-dense 64->64 + relu fused with pooling
    agg_kernel<64><<<((size_t)N * 16 + TB - 1) / TB, TB, 0, stream>>>(h1, csr_src, offsets, agg, N);
    gemm_dense_kernel<64, true><<<(N + 63) / 64, TB, 0, stream>>>(agg, h1, W2_l, W2_r, b2, nullptr,
                                                                  batch, pool, N);

    final_kernel<<<(G * 2 + TB - 1) / TB, TB, 0, stream>>>(pool, cnt, W_lin, b_lin, out, G);
}

// Round 10
// 535.917 us; speedup vs baseline: 7.0361x; 1.0972x over previous
//
#include <hip/hip_runtime.h>
#include <hip/hip_bf16.h>

// JetGNN: 2-layer SAGEConv(mean) + ReLU + global_mean_pool + Linear(64->2)
// R1: hierarchical scan. R2: bucketed counting-sort CSR build.
// R3: run-flush pool. R4: agg x4 unroll WIN. R5-R8: wave-uniform dense dead end.
// R9: dense as LDS-tiled GEMM (4x4 reg tile, permuted LDS rows) WIN (-176us).
// R10: agg is beyond-L2-BW-bound (FETCH 382MB = 8 XCD x 51MB h1, random
//      gather). Halve bytes: bf16 gather path (x->xb cvt; h1 stored bf16
//      only), fp32 accumulate. Dense math unchanged (fp32 from LDS).

#define WS_ALIGN 64
#define EPB 4096          // edges per block in bucket_scatter (256 thr x 16)
#define BSHIFT 10         // 1024 nodes per bucket
#define BNODES 1024

__device__ inline unsigned short f2bf(float f) {   // RNE f32->bf16 (finite inputs)
    unsigned u = __float_as_uint(f);
    return (unsigned short)((u + 0x7fffu + ((u >> 16) & 1u)) >> 16);
}

__device__ inline void acc8(const uint4 u, float* a) {  // 8 bf16 -> fp32 accumulate
    a[0] += __uint_as_float(u.x << 16);
    a[1] += __uint_as_float(u.x & 0xffff0000u);
    a[2] += __uint_as_float(u.y << 16);
    a[3] += __uint_as_float(u.y & 0xffff0000u);
    a[4] += __uint_as_float(u.z << 16);
    a[5] += __uint_as_float(u.z & 0xffff0000u);
    a[6] += __uint_as_float(u.w << 16);
    a[7] += __uint_as_float(u.w & 0xffff0000u);
}

// ---------- pooling counts ----------

__global__ void cnt_kernel(const int* __restrict__ batch, int* __restrict__ cnt, int N) {
    int i = blockIdx.x * blockDim.x + threadIdx.x;
    if (i < N) atomicAdd(&cnt[batch[i]], 1);
}

// ---------- x (f32) -> xb (bf16) ----------

__global__ void cvt_kernel(const float* __restrict__ x, unsigned short* __restrict__ xb,
                           int total4) {
    int i = blockIdx.x * blockDim.x + threadIdx.x;
    if (i >= total4) return;
    const float4 v = reinterpret_cast<const float4*>(x)[i];
    ushort4 o;
    o.x = f2bf(v.x); o.y = f2bf(v.y); o.z = f2bf(v.z); o.w = f2bf(v.w);
    reinterpret_cast<ushort4*>(xb)[i] = o;
}

// ---------- bucketed CSR construction ----------

__global__ __launch_bounds__(256) void bucket_hist_kernel(const int* __restrict__ dst,
                                                          int* __restrict__ bucketCount, int E) {
    __shared__ int hist[256];
    const int t = threadIdx.x;
    hist[t] = 0;
    __syncthreads();
    for (int e = blockIdx.x * blockDim.x + t; e < E; e += gridDim.x * blockDim.x)
        atomicAdd(&hist[dst[e] >> BSHIFT], 1);
    __syncthreads();
    if (hist[t] > 0) atomicAdd(&bucketCount[t], hist[t]);
}

__global__ __launch_bounds__(256) void bucket_scan_kernel(const int* __restrict__ bucketCount,
                                                          int* __restrict__ bucketBase,
                                                          int* __restrict__ bucketCursor,
                                                          int NB, int E) {
    __shared__ int s[256];
    const int t = threadIdx.x;
    int v = (t < NB) ? bucketCount[t] : 0;
    s[t] = v;
    __syncthreads();
    for (int off = 1; off < 256; off <<= 1) {
        int u = (t >= off) ? s[t - off] : 0;
        __syncthreads();
        s[t] += u;
        __syncthreads();
    }
    int excl = s[t] - v;
    if (t < NB) { bucketBase[t] = excl; bucketCursor[t] = excl; }
    if (t == 0) bucketBase[NB] = E;
}

__global__ __launch_bounds__(256) void bucket_scatter_kernel(const int* __restrict__ src,
                                                             const int* __restrict__ dst,
                                                             int* __restrict__ bucketCursor,
                                                             unsigned* __restrict__ bucketData,
                                                             int E, int NB) {
    __shared__ int hist[256];
    __shared__ int cur[256];
    const int t = threadIdx.x;
    hist[t] = 0;
    __syncthreads();
    const int eBase = blockIdx.x * EPB + t;
    int s[16], b[16], dl[16];
#pragma unroll
    for (int j = 0; j < 16; ++j) {
        int e = eBase + j * 256;
        if (e < E) {
            int d = dst[e];
            s[j]  = src[e];
            b[j]  = d >> BSHIFT;
            dl[j] = d & (BNODES - 1);
            atomicAdd(&hist[b[j]], 1);
        } else {
            b[j] = -1;
        }
    }
    __syncthreads();
    if (t < NB && hist[t] > 0) cur[t] = atomicAdd(&bucketCursor[t], hist[t]);
    __syncthreads();
#pragma unroll
    for (int j = 0; j < 16; ++j) {
        if (b[j] >= 0) {
            int pos = atomicAdd(&cur[b[j]], 1);
            bucketData[pos] = ((unsigned)s[j] << BSHIFT) | (unsigned)dl[j];
        }
    }
}

__global__ __launch_bounds__(256) void csr_build_kernel(const unsigned* __restrict__ bucketData,
                                                        const int* __restrict__ bucketBase,
                                                        int* __restrict__ offsets,
                                                        int* __restrict__ csr_src,
                                                        int N, int E, int NB) {
    __shared__ int cnt[BNODES];
    __shared__ int sscan[256];
    __shared__ int cur[BNODES];
    const int t   = threadIdx.x;
    const int bkt = blockIdx.x;
    const int beg = bucketBase[bkt];
    const int end = bucketBase[bkt + 1];
    for (int i = t; i < BNODES; i += 256) cnt[i] = 0;
    __syncthreads();
    for (int k = beg + t; k < end; k += 256)
        atomicAdd(&cnt[bucketData[k] & (BNODES - 1)], 1);
    __syncthreads();
    int local[4];
    int sum = 0;
#pragma unroll
    for (int j = 0; j < 4; ++j) { local[j] = sum; sum += cnt[t * 4 + j]; }
    sscan[t] = sum;
    __syncthreads();
    for (int off = 1; off < 256; off <<= 1) {
        int v = (t >= off) ? sscan[t - off] : 0;
        __syncthreads();
        sscan[t] += v;
        __syncthreads();
    }
    int base = (t > 0) ? sscan[t - 1] : 0;
#pragma unroll
    for (int j = 0; j < 4; ++j) cur[t * 4 + j] = base + local[j];
    __syncthreads();
    for (int i = t; i < BNODES; i += 256) {
        int node = (bkt << BSHIFT) + i;
        if (node <= N) offsets[node] = beg + cur[i];
    }
    if (bkt == NB - 1 && t == 0 && (NB << BSHIFT) == N) offsets[N] = E;
    __syncthreads();
    for (int k = beg + t; k < end; k += 256) {
        unsigned v = bucketData[k];
        int d   = (int)(v & (BNODES - 1));
        int pos = beg + atomicAdd(&cur[d], 1);
        csr_src[pos] = (int)(v >> BSHIFT);
    }
}

// ---------- mean aggregation from bf16 features (fp32 accumulate) ----------
// D/8 lanes per node; each lane owns 8 channels (one 16B uint4 per neighbor).
// x4 neighbor unroll -> 4 gathers in flight (R4 win preserved).

template <int D>
__global__ void agg_bf16_kernel(const unsigned short* __restrict__ featb,
                                const int* __restrict__ csr_src,
                                const int* __restrict__ offsets,
                                float* __restrict__ agg, int N) {
    constexpr int TPN = D / 8;
    int tid  = blockIdx.x * blockDim.x + threadIdx.x;
    int node = tid / TPN;
    int part = tid % TPN;
    if (node >= N) return;
    const int beg = offsets[node];
    const int end = offsets[node + 1];
    const uint4* base = reinterpret_cast<const uint4*>(featb);
    float a[8] = {0.f, 0.f, 0.f, 0.f, 0.f, 0.f, 0.f, 0.f};
    int k = beg;
    for (; k + 4 <= end; k += 4) {
        const int s0 = csr_src[k + 0];
        const int s1 = csr_src[k + 1];
        const int s2 = csr_src[k + 2];
        const int s3 = csr_src[k + 3];
        const uint4 u0 = base[(size_t)s0 * TPN + part];
        const uint4 u1 = base[(size_t)s1 * TPN + part];
        const uint4 u2 = base[(size_t)s2 * TPN + part];
        const uint4 u3 = base[(size_t)s3 * TPN + part];
        acc8(u0, a); acc8(u1, a); acc8(u2, a); acc8(u3, a);
    }
    for (; k < end; ++k) {
        const uint4 u = base[(size_t)csr_src[k] * TPN + part];
        acc8(u, a);
    }
    const float inv = 1.0f / fmaxf((float)(end - beg), 1.0f);
    float4 lo = make_float4(a[0] * inv, a[1] * inv, a[2] * inv, a[3] * inv);
    float4 hi = make_float4(a[4] * inv, a[5] * inv, a[6] * inv, a[7] * inv);
    float* dstp = agg + (size_t)node * D + part * 8;
    *reinterpret_cast<float4*>(dstp)     = lo;
    *reinterpret_cast<float4*>(dstp + 4) = hi;
}

// ---------- dense as LDS-tiled GEMM ----------
// C[64 nodes][64 outs]/block = [agg|xin] @ [Wl|Wr]^T, K = 2*DIN.
// 4x4 register tile/thread; bit-permuted LDS rows (odd f4 stride).
// XBF16: xin slab staged from bf16 (layer 2: xin = h1b).
// Non-POOL epilogue writes bf16 (h1b) only.

template <int DIN, bool POOL, bool XBF16>
__launch_bounds__(256)
__global__ void gemm_dense_kernel(const float* __restrict__ agg,
                                  const float* __restrict__ xinf,
                                  const unsigned short* __restrict__ xinb,
                                  const float* __restrict__ Wl,
                                  const float* __restrict__ Wr,
                                  const float* __restrict__ bias,
                                  unsigned short* __restrict__ houtb,
                                  const int* __restrict__ batch,
                                  float* __restrict__ pool_sum,
                                  int N) {
    constexpr int K   = 2 * DIN;    // 64 or 128
    constexpr int K4  = K / 4;      // 16 or 32
    constexpr int WS4 = K4 + 1;     // w_s row stride (float4), odd
    constexpr int AS4 = 17;         // a_s row stride (float4), odd
    constexpr int D4  = DIN / 4;
    constexpr int NPH = K / 64;     // k-phases
    __shared__ float4 w_s[64 * WS4];
    __shared__ float4 a_s[64 * AS4];
    const int tid = threadIdx.x;
    const int ti = tid >> 4;        // node group 0..15
    const int tj = tid & 15;        // out group 0..15
    const int nodeBase = blockIdx.x * 64;

    // stage weights: w_s[perm(o)][k] = [Wl[o] | Wr[o]]
    for (int g = tid; g < 64 * K4; g += 256) {
        const int o  = g / K4;
        const int c4 = g % K4;
        const float4 v = (c4 < D4)
            ? *reinterpret_cast<const float4*>(Wl + (size_t)o * DIN + c4 * 4)
            : *reinterpret_cast<const float4*>(Wr + (size_t)o * DIN + (c4 - D4) * 4);
        const int oP = ((o & 3) << 4) | (o >> 2);
        w_s[oP * WS4 + c4] = v;
    }

    const float4 bv = *reinterpret_cast<const float4*>(bias + tj * 4);
    float acc[4][4];
#pragma unroll
    for (int i = 0; i < 4; ++i) {
        acc[i][0] = bv.x; acc[i][1] = bv.y; acc[i][2] = bv.z; acc[i][3] = bv.w;
    }

    for (int p = 0; p < NPH; ++p) {
        __syncthreads();
        if constexpr (XBF16) {
            if (p == 0) {
                // agg slab (f32), gk4 in [0,16) all < D4
                for (int g = tid; g < 64 * 16; g += 256) {
                    const int node = g >> 4;
                    const int k4   = g & 15;
                    const int n = min(nodeBase + node, N - 1);
                    const float4 v = *reinterpret_cast<const float4*>(
                        agg + (size_t)n * DIN + k4 * 4);
                    const int nP = ((node & 3) << 4) | (node >> 2);
                    a_s[nP * AS4 + k4] = v;
                }
            } else {
                // xin slab from bf16: row = DIN ushorts = DIN/8 uint4s
                for (int g = tid; g < 64 * (DIN / 8); g += 256) {
                    const int node = g >> 3;
                    const int q    = g & 7;
                    const int n = min(nodeBase + node, N - 1);
                    const uint4 u = *reinterpret_cast<const uint4*>(
                        xinb + (size_t)n * DIN + q * 8);
                    float4 lo, hi;
                    lo.x = __uint_as_float(u.x << 16);
                    lo.y = __uint_as_float(u.x & 0xffff0000u);
                    lo.z = __uint_as_float(u.y << 16);
                    lo.w = __uint_as_float(u.y & 0xffff0000u);
                    hi.x = __uint_as_float(u.z << 16);
                    hi.y = __uint_as_float(u.z & 0xffff0000u);
                    hi.z = __uint_as_float(u.w << 16);
                    hi.w = __uint_as_float(u.w & 0xffff0000u);
                    const int nP = ((node & 3) << 4) | (node >> 2);
                    a_s[nP * AS4 + 2 * q]     = lo;
                    a_s[nP * AS4 + 2 * q + 1] = hi;
                }
            }
        } else {
            // mixed f32 slab (layer 1: agg then x, both f32)
            for (int g = tid; g < 64 * 16; g += 256) {
                const int node = g >> 4;
                const int k4   = g & 15;
                const int gk4  = p * 16 + k4;
                const int n = min(nodeBase + node, N - 1);
                const float4 v = (gk4 < D4)
                    ? *reinterpret_cast<const float4*>(agg + (size_t)n * DIN + gk4 * 4)
                    : *reinterpret_cast<const float4*>(xinf + (size_t)n * DIN + (gk4 - D4) * 4);
                const int nP = ((node & 3) << 4) | (node >> 2);
                a_s[nP * AS4 + k4] = v;
            }
        }
        __syncthreads();
#pragma unroll
        for (int k4 = 0; k4 < 16; ++k4) {
            float4 av[4], wv[4];
#pragma unroll
            for (int i = 0; i < 4; ++i)
                av[i] = a_s[(ti + 16 * i) * AS4 + k4];     // perm(ti*4+i) = ti+16i
#pragma unroll
            for (int j = 0; j < 4; ++j)
                wv[j] = w_s[(tj + 16 * j) * WS4 + p * 16 + k4];
#pragma unroll
            for (int i = 0; i < 4; ++i)
#pragma unroll
                for (int j = 0; j < 4; ++j) {
                    acc[i][j] = fmaf(av[i].x, wv[j].x, acc[i][j]);
                    acc[i][j] = fmaf(av[i].y, wv[j].y, acc[i][j]);
                    acc[i][j] = fmaf(av[i].z, wv[j].z, acc[i][j]);
                    acc[i][j] = fmaf(av[i].w, wv[j].w, acc[i][j]);
                }
        }
    }

#pragma unroll
    for (int i = 0; i < 4; ++i)
#pragma unroll
        for (int j = 0; j < 4; ++j)
            acc[i][j] = fmaxf(acc[i][j], 0.0f);

    if (POOL) {
        float ag0 = 0.f, ag1 = 0.f, ag2 = 0.f, ag3 = 0.f;
        int gcur = -1;
#pragma unroll
        for (int i = 0; i < 4; ++i) {
            const int n = nodeBase + ti * 4 + i;
            if (n < N) {
                const int g = batch[n];      // sorted
                if (g != gcur) {
                    if (gcur >= 0) {
                        atomicAdd(&pool_sum[(size_t)gcur * 64 + tj * 4 + 0], ag0);
                        atomicAdd(&pool_sum[(size_t)gcur * 64 + tj * 4 + 1], ag1);
                        atomicAdd(&pool_sum[(size_t)gcur * 64 + tj * 4 + 2], ag2);
                        atomicAdd(&pool_sum[(size_t)gcur * 64 + tj * 4 + 3], ag3);
                    }
                    gcur = g; ag0 = ag1 = ag2 = ag3 = 0.f;
                }
                ag0 += acc[i][0]; ag1 += acc[i][1]; ag2 += acc[i][2]; ag3 += acc[i][3];
            }
        }
        if (gcur >= 0) {
            atomicAdd(&pool_sum[(size_t)gcur * 64 + tj * 4 + 0], ag0);
            atomicAdd(&pool_sum[(size_t)gcur * 64 + tj * 4 + 1], ag1);
            atomicAdd(&pool_sum[(size_t)gcur * 64 + tj * 4 + 2], ag2);
            atomicAdd(&pool_sum[(size_t)gcur * 64 + tj * 4 + 3], ag3);
        }
    } else {
#pragma unroll
        for (int i = 0; i < 4; ++i) {
            const int n = nodeBase + ti * 4 + i;
            if (n < N) {
                ushort4 o;
                o.x = f2bf(acc[i][0]); o.y = f2bf(acc[i][1]);
                o.z = f2bf(acc[i][2]); o.w = f2bf(acc[i][3]);
                *reinterpret_cast<ushort4*>(houtb + (size_t)n * 64 + tj * 4) = o;
            }
        }
    }
}

// ---------- head ----------

__global__ void final_kernel(const float* __restrict__ pool_sum,
                             const int* __restrict__ cnt,
                             const float* __restrict__ W_lin,
                             const float* __restrict__ b_lin,
                             float* __restrict__ out, int G) {
    int t = blockIdx.x * blockDim.x + threadIdx.x;
    if (t >= G * 2) return;
    int g = t >> 1, o = t & 1;
    float inv = 1.0f / fmaxf((float)cnt[g], 1.0f);
    float acc = b_lin[o];
#pragma unroll
    for (int c = 0; c < 64; ++c)
        acc = fmaf(pool_sum[(size_t)g * 64 + c] * inv, W_lin[o * 64 + c], acc);
    out[t] = acc;
}

extern "C" void kernel_launch(void* const* d_in, const int* in_sizes, int n_in,
                              void* d_out, int out_size, void* d_ws, size_t ws_size,
                              hipStream_t stream) {
    const float* x     = (const float*)d_in[0];
    const int*   ei    = (const int*)d_in[1];
    const int*   batch = (const int*)d_in[2];
    const float* W1_l  = (const float*)d_in[3];
    const float* b1    = (const float*)d_in[4];
    const float* W1_r  = (const float*)d_in[5];
    const float* W2_l  = (const float*)d_in[6];
    const float* b2    = (const float*)d_in[7];
    const float* W2_r  = (const float*)d_in[8];
    const float* W_lin = (const float*)d_in[9];
    const float* b_lin = (const float*)d_in[10];

    const int N = in_sizes[0] / 32;
    const int E = in_sizes[1] / 2;
    const int G = out_size / 2;
    const int* src = ei;
    const int* dst = ei + E;
    const int NB = (N + BNODES - 1) >> BSHIFT;   // 196 for N=200000

    char* p = (char*)d_ws;
    auto carve = [&](size_t bytes) -> void* {
        void* r = (void*)p;
        p += (bytes + (WS_ALIGN - 1)) / WS_ALIGN * WS_ALIGN;
        return r;
    };
    int*            bucketCount  = (int*)carve(256 * 4);
    int*            bucketBase   = (int*)carve(257 * 4);
    int*            bucketCursor = (int*)carve(256 * 4);
    unsigned*       bucketData   = (unsigned*)carve((size_t)E * 4);
    int*            offsets      = (int*)carve((size_t)(N + 1) * 4);
    int*            csr_src      = (int*)carve((size_t)E * 4);
    float*          agg          = (float*)carve((size_t)N * 64 * 4);
    unsigned short* xb           = (unsigned short*)carve((size_t)N * 32 * 2);
    unsigned short* h1b          = (unsigned short*)carve((size_t)N * 64 * 2);
    float*          pool         = (float*)carve((size_t)G * 64 * 4);
    int*            cnt          = (int*)carve((size_t)G * 4);
    float*          out          = (float*)d_out;

    hipMemsetAsync(bucketCount, 0, 256 * 4, stream);
    hipMemsetAsync(pool, 0, (size_t)G * 64 * 4, stream);
    hipMemsetAsync(cnt, 0, (size_t)G * 4, stream);

    const int TB = 256;
    cnt_kernel<<<(N + TB - 1) / TB, TB, 0, stream>>>(batch, cnt, N);
    cvt_kernel<<<((N * 32 / 4) + TB - 1) / TB, TB, 0, stream>>>(x, xb, N * 32 / 4);
    bucket_hist_kernel<<<1024, TB, 0, stream>>>(dst, bucketCount, E);
    bucket_scan_kernel<<<1, TB, 0, stream>>>(bucketCount, bucketBase, bucketCursor, NB, E);
    bucket_scatter_kernel<<<(E + EPB - 1) / EPB, TB, 0, stream>>>(src, dst, bucketCursor,
                                                                  bucketData, E, NB);
    csr_build_kernel<<<NB, TB, 0, stream>>>(bucketData, bucketBase, offsets, csr_src, N, E, NB);

    // layer 1: bf16 gather-mean of x (D=32), GEMM 32->64 + relu -> h1b (bf16)
    agg_bf16_kernel<32><<<((size_t)N * 4 + TB - 1) / TB, TB, 0, stream>>>(xb, csr_src,
                                                                          offsets, agg, N);
    gemm_dense_kernel<32, false, false><<<(N + 63) / 64, TB, 0, stream>>>(
        agg, x, nullptr, W1_l, W1_r, b1, h1b, nullptr, nullptr, N);

    // layer 2: bf16 gather-mean of h1b (D=64), GEMM 64->64 + relu + pool
    agg_bf16_kernel<64><<<((size_t)N * 8 + TB - 1) / TB, TB, 0, stream>>>(h1b, csr_src,
                                                                          offsets, agg, N);
    gemm_dense_kernel<64, true, true><<<(N + 63) / 64, TB, 0, stream>>>(
        agg, nullptr, h1b, W2_l, W2_r, b2, nullptr, batch, pool, N);

    final_kernel<<<(G * 2 + TB - 1) / TB, TB, 0, stream>>>(pool, cnt, W_lin, b_lin, out, G);
}

// Round 11
// 466.361 us; speedup vs baseline: 8.0855x; 1.1491x over previous
//
#include <hip/hip_runtime.h>
#include <hip/hip_bf16.h>

// JetGNN: 2-layer SAGEConv(mean) + ReLU + global_mean_pool + Linear(64->2)
// R1: hierarchical scan. R2: bucketed counting-sort CSR build.
// R3: run-flush pool. R4: agg x4 unroll WIN. R5-R8: wave-uniform dense dead end
//     (compiler hoist -> VGPR 204 / spill 10.8GB; unroll pragmas IGNORED).
// R9: dense as LDS-tiled GEMM WIN. R10: bf16 gather path WIN (agg halved,
//     absmax 4.9e-4 < 2e-3) -- but gemm itself VGPR 240 / occ 10.6% / 120us:
//     full unroll of the 16-iter k4 loop pipelines 8 f4 LDS loads deep.
// R11: k4 loop trip count made RUNTIME (kernel arg) -- compiler cannot fully
//     unroll; live set ~90 VGPR -> 4-5 waves/SIMD. Pragma-free by design.

#define WS_ALIGN 64
#define EPB 4096          // edges per block in bucket_scatter (256 thr x 16)
#define BSHIFT 10         // 1024 nodes per bucket
#define BNODES 1024

__device__ inline unsigned short f2bf(float f) {   // RNE f32->bf16 (finite inputs)
    unsigned u = __float_as_uint(f);
    return (unsigned short)((u + 0x7fffu + ((u >> 16) & 1u)) >> 16);
}

__device__ inline void acc8(const uint4 u, float* a) {  // 8 bf16 -> fp32 accumulate
    a[0] += __uint_as_float(u.x << 16);
    a[1] += __uint_as_float(u.x & 0xffff0000u);
    a[2] += __uint_as_float(u.y << 16);
    a[3] += __uint_as_float(u.y & 0xffff0000u);
    a[4] += __uint_as_float(u.z << 16);
    a[5] += __uint_as_float(u.z & 0xffff0000u);
    a[6] += __uint_as_float(u.w << 16);
    a[7] += __uint_as_float(u.w & 0xffff0000u);
}

// ---------- pooling counts ----------

__global__ void cnt_kernel(const int* __restrict__ batch, int* __restrict__ cnt, int N) {
    int i = blockIdx.x * blockDim.x + threadIdx.x;
    if (i < N) atomicAdd(&cnt[batch[i]], 1);
}

// ---------- x (f32) -> xb (bf16) ----------

__global__ void cvt_kernel(const float* __restrict__ x, unsigned short* __restrict__ xb,
                           int total4) {
    int i = blockIdx.x * blockDim.x + threadIdx.x;
    if (i >= total4) return;
    const float4 v = reinterpret_cast<const float4*>(x)[i];
    ushort4 o;
    o.x = f2bf(v.x); o.y = f2bf(v.y); o.z = f2bf(v.z); o.w = f2bf(v.w);
    reinterpret_cast<ushort4*>(xb)[i] = o;
}

// ---------- bucketed CSR construction ----------

__global__ __launch_bounds__(256) void bucket_hist_kernel(const int* __restrict__ dst,
                                                          int* __restrict__ bucketCount, int E) {
    __shared__ int hist[256];
    const int t = threadIdx.x;
    hist[t] = 0;
    __syncthreads();
    for (int e = blockIdx.x * blockDim.x + t; e < E; e += gridDim.x * blockDim.x)
        atomicAdd(&hist[dst[e] >> BSHIFT], 1);
    __syncthreads();
    if (hist[t] > 0) atomicAdd(&bucketCount[t], hist[t]);
}

__global__ __launch_bounds__(256) void bucket_scan_kernel(const int* __restrict__ bucketCount,
                                                          int* __restrict__ bucketBase,
                                                          int* __restrict__ bucketCursor,
                                                          int NB, int E) {
    __shared__ int s[256];
    const int t = threadIdx.x;
    int v = (t < NB) ? bucketCount[t] : 0;
    s[t] = v;
    __syncthreads();
    for (int off = 1; off < 256; off <<= 1) {
        int u = (t >= off) ? s[t - off] : 0;
        __syncthreads();
        s[t] += u;
        __syncthreads();
    }
    int excl = s[t] - v;
    if (t < NB) { bucketBase[t] = excl; bucketCursor[t] = excl; }
    if (t == 0) bucketBase[NB] = E;
}

__global__ __launch_bounds__(256) void bucket_scatter_kernel(const int* __restrict__ src,
                                                             const int* __restrict__ dst,
                                                             int* __restrict__ bucketCursor,
                                                             unsigned* __restrict__ bucketData,
                                                             int E, int NB) {
    __shared__ int hist[256];
    __shared__ int cur[256];
    const int t = threadIdx.x;
    hist[t] = 0;
    __syncthreads();
    const int eBase = blockIdx.x * EPB + t;
    int s[16], b[16], dl[16];
#pragma unroll
    for (int j = 0; j < 16; ++j) {
        int e = eBase + j * 256;
        if (e < E) {
            int d = dst[e];
            s[j]  = src[e];
            b[j]  = d >> BSHIFT;
            dl[j] = d & (BNODES - 1);
            atomicAdd(&hist[b[j]], 1);
        } else {
            b[j] = -1;
        }
    }
    __syncthreads();
    if (t < NB && hist[t] > 0) cur[t] = atomicAdd(&bucketCursor[t], hist[t]);
    __syncthreads();
#pragma unroll
    for (int j = 0; j < 16; ++j) {
        if (b[j] >= 0) {
            int pos = atomicAdd(&cur[b[j]], 1);
            bucketData[pos] = ((unsigned)s[j] << BSHIFT) | (unsigned)dl[j];
        }
    }
}

__global__ __launch_bounds__(256) void csr_build_kernel(const unsigned* __restrict__ bucketData,
                                                        const int* __restrict__ bucketBase,
                                                        int* __restrict__ offsets,
                                                        int* __restrict__ csr_src,
                                                        int N, int E, int NB) {
    __shared__ int cnt[BNODES];
    __shared__ int sscan[256];
    __shared__ int cur[BNODES];
    const int t   = threadIdx.x;
    const int bkt = blockIdx.x;
    const int beg = bucketBase[bkt];
    const int end = bucketBase[bkt + 1];
    for (int i = t; i < BNODES; i += 256) cnt[i] = 0;
    __syncthreads();
    for (int k = beg + t; k < end; k += 256)
        atomicAdd(&cnt[bucketData[k] & (BNODES - 1)], 1);
    __syncthreads();
    int local[4];
    int sum = 0;
#pragma unroll
    for (int j = 0; j < 4; ++j) { local[j] = sum; sum += cnt[t * 4 + j]; }
    sscan[t] = sum;
    __syncthreads();
    for (int off = 1; off < 256; off <<= 1) {
        int v = (t >= off) ? sscan[t - off] : 0;
        __syncthreads();
        sscan[t] += v;
        __syncthreads();
    }
    int base = (t > 0) ? sscan[t - 1] : 0;
#pragma unroll
    for (int j = 0; j < 4; ++j) cur[t * 4 + j] = base + local[j];
    __syncthreads();
    for (int i = t; i < BNODES; i += 256) {
        int node = (bkt << BSHIFT) + i;
        if (node <= N) offsets[node] = beg + cur[i];
    }
    if (bkt == NB - 1 && t == 0 && (NB << BSHIFT) == N) offsets[N] = E;
    __syncthreads();
    for (int k = beg + t; k < end; k += 256) {
        unsigned v = bucketData[k];
        int d   = (int)(v & (BNODES - 1));
        int pos = beg + atomicAdd(&cur[d], 1);
        csr_src[pos] = (int)(v >> BSHIFT);
    }
}

// ---------- mean aggregation from bf16 features (fp32 accumulate) ----------

template <int D>
__global__ void agg_bf16_kernel(const unsigned short* __restrict__ featb,
                                const int* __restrict__ csr_src,
                                const int* __restrict__ offsets,
                                float* __restrict__ agg, int N) {
    constexpr int TPN = D / 8;
    int tid  = blockIdx.x * blockDim.x + threadIdx.x;
    int node = tid / TPN;
    int part = tid % TPN;
    if (node >= N) return;
    const int beg = offsets[node];
    const int end = offsets[node + 1];
    const uint4* base = reinterpret_cast<const uint4*>(featb);
    float a[8] = {0.f, 0.f, 0.f, 0.f, 0.f, 0.f, 0.f, 0.f};
    int k = beg;
    for (; k + 4 <= end; k += 4) {
        const int s0 = csr_src[k + 0];
        const int s1 = csr_src[k + 1];
        const int s2 = csr_src[k + 2];
        const int s3 = csr_src[k + 3];
        const uint4 u0 = base[(size_t)s0 * TPN + part];
        const uint4 u1 = base[(size_t)s1 * TPN + part];
        const uint4 u2 = base[(size_t)s2 * TPN + part];
        const uint4 u3 = base[(size_t)s3 * TPN + part];
        acc8(u0, a); acc8(u1, a); acc8(u2, a); acc8(u3, a);
    }
    for (; k < end; ++k) {
        const uint4 u = base[(size_t)csr_src[k] * TPN + part];
        acc8(u, a);
    }
    const float inv = 1.0f / fmaxf((float)(end - beg), 1.0f);
    float4 lo = make_float4(a[0] * inv, a[1] * inv, a[2] * inv, a[3] * inv);
    float4 hi = make_float4(a[4] * inv, a[5] * inv, a[6] * inv, a[7] * inv);
    float* dstp = agg + (size_t)node * D + part * 8;
    *reinterpret_cast<float4*>(dstp)     = lo;
    *reinterpret_cast<float4*>(dstp + 4) = hi;
}

// ---------- dense as LDS-tiled GEMM ----------
// C[64 nodes][64 outs]/block = [agg|xin] @ [Wl|Wr]^T, K = 2*DIN.
// 4x4 register tile/thread; bit-permuted LDS rows (odd f4 stride).
// kIter is a RUNTIME arg (always 16): prevents full unroll of the k4 loop
// (R10: full unroll -> VGPR 240, occ 10.6%).

template <int DIN, bool POOL, bool XBF16>
__launch_bounds__(256)
__global__ void gemm_dense_kernel(const float* __restrict__ agg,
                                  const float* __restrict__ xinf,
                                  const unsigned short* __restrict__ xinb,
                                  const float* __restrict__ Wl,
                                  const float* __restrict__ Wr,
                                  const float* __restrict__ bias,
                                  unsigned short* __restrict__ houtb,
                                  const int* __restrict__ batch,
                                  float* __restrict__ pool_sum,
                                  int N, int kIter) {
    constexpr int K   = 2 * DIN;    // 64 or 128
    constexpr int K4  = K / 4;      // 16 or 32
    constexpr int WS4 = K4 + 1;     // w_s row stride (float4), odd
    constexpr int AS4 = 17;         // a_s row stride (float4), odd
    constexpr int D4  = DIN / 4;
    constexpr int NPH = K / 64;     // k-phases
    __shared__ float4 w_s[64 * WS4];
    __shared__ float4 a_s[64 * AS4];
    const int tid = threadIdx.x;
    const int ti = tid >> 4;        // node group 0..15
    const int tj = tid & 15;        // out group 0..15
    const int nodeBase = blockIdx.x * 64;

    // stage weights: w_s[perm(o)][k] = [Wl[o] | Wr[o]]
    for (int g = tid; g < 64 * K4; g += 256) {
        const int o  = g / K4;
        const int c4 = g % K4;
        const float4 v = (c4 < D4)
            ? *reinterpret_cast<const float4*>(Wl + (size_t)o * DIN + c4 * 4)
            : *reinterpret_cast<const float4*>(Wr + (size_t)o * DIN + (c4 - D4) * 4);
        const int oP = ((o & 3) << 4) | (o >> 2);
        w_s[oP * WS4 + c4] = v;
    }

    const float4 bv = *reinterpret_cast<const float4*>(bias + tj * 4);
    float acc[4][4];
#pragma unroll
    for (int i = 0; i < 4; ++i) {
        acc[i][0] = bv.x; acc[i][1] = bv.y; acc[i][2] = bv.z; acc[i][3] = bv.w;
    }

    for (int p = 0; p < NPH; ++p) {
        __syncthreads();
        if constexpr (XBF16) {
            if (p == 0) {
                for (int g = tid; g < 64 * 16; g += 256) {
                    const int node = g >> 4;
                    const int k4   = g & 15;
                    const int n = min(nodeBase + node, N - 1);
                    const float4 v = *reinterpret_cast<const float4*>(
                        agg + (size_t)n * DIN + k4 * 4);
                    const int nP = ((node & 3) << 4) | (node >> 2);
                    a_s[nP * AS4 + k4] = v;
                }
            } else {
                for (int g = tid; g < 64 * (DIN / 8); g += 256) {
                    const int node = g >> 3;
                    const int q    = g & 7;
                    const int n = min(nodeBase + node, N - 1);
                    const uint4 u = *reinterpret_cast<const uint4*>(
                        xinb + (size_t)n * DIN + q * 8);
                    float4 lo, hi;
                    lo.x = __uint_as_float(u.x << 16);
                    lo.y = __uint_as_float(u.x & 0xffff0000u);
                    lo.z = __uint_as_float(u.y << 16);
                    lo.w = __uint_as_float(u.y & 0xffff0000u);
                    hi.x = __uint_as_float(u.z << 16);
                    hi.y = __uint_as_float(u.z & 0xffff0000u);
                    hi.z = __uint_as_float(u.w << 16);
                    hi.w = __uint_as_float(u.w & 0xffff0000u);
                    const int nP = ((node & 3) << 4) | (node >> 2);
                    a_s[nP * AS4 + 2 * q]     = lo;
                    a_s[nP * AS4 + 2 * q + 1] = hi;
                }
            }
        } else {
            for (int g = tid; g < 64 * 16; g += 256) {
                const int node = g >> 4;
                const int k4   = g & 15;
                const int gk4  = p * 16 + k4;
                const int n = min(nodeBase + node, N - 1);
                const float4 v = (gk4 < D4)
                    ? *reinterpret_cast<const float4*>(agg + (size_t)n * DIN + gk4 * 4)
                    : *reinterpret_cast<const float4*>(xinf + (size_t)n * DIN + (gk4 - D4) * 4);
                const int nP = ((node & 3) << 4) | (node >> 2);
                a_s[nP * AS4 + k4] = v;
            }
        }
        __syncthreads();
        // per-thread row pointers; runtime kIter (=16) forbids full unroll
        const float4* a0p = a_s + (ti +  0) * AS4;
        const float4* a1p = a_s + (ti + 16) * AS4;
        const float4* a2p = a_s + (ti + 32) * AS4;
        const float4* a3p = a_s + (ti + 48) * AS4;
        const float4* w0p = w_s + (tj +  0) * WS4 + p * 16;
        const float4* w1p = w_s + (tj + 16) * WS4 + p * 16;
        const float4* w2p = w_s + (tj + 32) * WS4 + p * 16;
        const float4* w3p = w_s + (tj + 48) * WS4 + p * 16;
        for (int k4 = 0; k4 < kIter; ++k4) {
            float4 av[4], wv[4];
            av[0] = a0p[k4]; av[1] = a1p[k4]; av[2] = a2p[k4]; av[3] = a3p[k4];
            wv[0] = w0p[k4]; wv[1] = w1p[k4]; wv[2] = w2p[k4]; wv[3] = w3p[k4];
#pragma unroll
            for (int i = 0; i < 4; ++i)
#pragma unroll
                for (int j = 0; j < 4; ++j) {
                    acc[i][j] = fmaf(av[i].x, wv[j].x, acc[i][j]);
                    acc[i][j] = fmaf(av[i].y, wv[j].y, acc[i][j]);
                    acc[i][j] = fmaf(av[i].z, wv[j].z, acc[i][j]);
                    acc[i][j] = fmaf(av[i].w, wv[j].w, acc[i][j]);
                }
        }
    }

#pragma unroll
    for (int i = 0; i < 4; ++i)
#pragma unroll
        for (int j = 0; j < 4; ++j)
            acc[i][j] = fmaxf(acc[i][j], 0.0f);

    if (POOL) {
        float ag0 = 0.f, ag1 = 0.f, ag2 = 0.f, ag3 = 0.f;
        int gcur = -1;
#pragma unroll
        for (int i = 0; i < 4; ++i) {
            const int n = nodeBase + ti * 4 + i;
            if (n < N) {
                const int g = batch[n];      // sorted
                if (g != gcur) {
                    if (gcur >= 0) {
                        atomicAdd(&pool_sum[(size_t)gcur * 64 + tj * 4 + 0], ag0);
                        atomicAdd(&pool_sum[(size_t)gcur * 64 + tj * 4 + 1], ag1);
                        atomicAdd(&pool_sum[(size_t)gcur * 64 + tj * 4 + 2], ag2);
                        atomicAdd(&pool_sum[(size_t)gcur * 64 + tj * 4 + 3], ag3);
                    }
                    gcur = g; ag0 = ag1 = ag2 = ag3 = 0.f;
                }
                ag0 += acc[i][0]; ag1 += acc[i][1]; ag2 += acc[i][2]; ag3 += acc[i][3];
            }
        }
        if (gcur >= 0) {
            atomicAdd(&pool_sum[(size_t)gcur * 64 + tj * 4 + 0], ag0);
            atomicAdd(&pool_sum[(size_t)gcur * 64 + tj * 4 + 1], ag1);
            atomicAdd(&pool_sum[(size_t)gcur * 64 + tj * 4 + 2], ag2);
            atomicAdd(&pool_sum[(size_t)gcur * 64 + tj * 4 + 3], ag3);
        }
    } else {
#pragma unroll
        for (int i = 0; i < 4; ++i) {
            const int n = nodeBase + ti * 4 + i;
            if (n < N) {
                ushort4 o;
                o.x = f2bf(acc[i][0]); o.y = f2bf(acc[i][1]);
                o.z = f2bf(acc[i][2]); o.w = f2bf(acc[i][3]);
                *reinterpret_cast<ushort4*>(houtb + (size_t)n * 64 + tj * 4) = o;
            }
        }
    }
}

// ---------- head ----------

__global__ void final_kernel(const float* __restrict__ pool_sum,
                             const int* __restrict__ cnt,
                             const float* __restrict__ W_lin,
                             const float* __restrict__ b_lin,
                             float* __restrict__ out, int G) {
    int t = blockIdx.x * blockDim.x + threadIdx.x;
    if (t >= G * 2) return;
    int g = t >> 1, o = t & 1;
    float inv = 1.0f / fmaxf((float)cnt[g], 1.0f);
    float acc = b_lin[o];
#pragma unroll
    for (int c = 0; c < 64; ++c)
        acc = fmaf(pool_sum[(size_t)g * 64 + c] * inv, W_lin[o * 64 + c], acc);
    out[t] = acc;
}

extern "C" void kernel_launch(void* const* d_in, const int* in_sizes, int n_in,
                              void* d_out, int out_size, void* d_ws, size_t ws_size,
                              hipStream_t stream) {
    const float* x     = (const float*)d_in[0];
    const int*   ei    = (const int*)d_in[1];
    const int*   batch = (const int*)d_in[2];
    const float* W1_l  = (const float*)d_in[3];
    const float* b1    = (const float*)d_in[4];
    const float* W1_r  = (const float*)d_in[5];
    const float* W2_l  = (const float*)d_in[6];
    const float* b2    = (const float*)d_in[7];
    const float* W2_r  = (const float*)d_in[8];
    const float* W_lin = (const float*)d_in[9];
    const float* b_lin = (const float*)d_in[10];

    const int N = in_sizes[0] / 32;
    const int E = in_sizes[1] / 2;
    const int G = out_size / 2;
    const int* src = ei;
    const int* dst = ei + E;
    const int NB = (N + BNODES - 1) >> BSHIFT;   // 196 for N=200000

    char* p = (char*)d_ws;
    auto carve = [&](size_t bytes) -> void* {
        void* r = (void*)p;
        p += (bytes + (WS_ALIGN - 1)) / WS_ALIGN * WS_ALIGN;
        return r;
    };
    int*            bucketCount  = (int*)carve(256 * 4);
    int*            bucketBase   = (int*)carve(257 * 4);
    int*            bucketCursor = (int*)carve(256 * 4);
    unsigned*       bucketData   = (unsigned*)carve((size_t)E * 4);
    int*            offsets      = (int*)carve((size_t)(N + 1) * 4);
    int*            csr_src      = (int*)carve((size_t)E * 4);
    float*          agg          = (float*)carve((size_t)N * 64 * 4);
    unsigned short* xb           = (unsigned short*)carve((size_t)N * 32 * 2);
    unsigned short* h1b          = (unsigned short*)carve((size_t)N * 64 * 2);
    float*          pool         = (float*)carve((size_t)G * 64 * 4);
    int*            cnt          = (int*)carve((size_t)G * 4);
    float*          out          = (float*)d_out;

    hipMemsetAsync(bucketCount, 0, 256 * 4, stream);
    hipMemsetAsync(pool, 0, (size_t)G * 64 * 4, stream);
    hipMemsetAsync(cnt, 0, (size_t)G * 4, stream);

    const int TB = 256;
    cnt_kernel<<<(N + TB - 1) / TB, TB, 0, stream>>>(batch, cnt, N);
    cvt_kernel<<<((N * 32 / 4) + TB - 1) / TB, TB, 0, stream>>>(x, xb, N * 32 / 4);
    bucket_hist_kernel<<<1024, TB, 0, stream>>>(dst, bucketCount, E);
    bucket_scan_kernel<<<1, TB, 0, stream>>>(bucketCount, bucketBase, bucketCursor, NB, E);
    bucket_scatter_kernel<<<(E + EPB - 1) / EPB, TB, 0, stream>>>(src, dst, bucketCursor,
                                                                  bucketData, E, NB);
    csr_build_kernel<<<NB, TB, 0, stream>>>(bucketData, bucketBase, offsets, csr_src, N, E, NB);

    // layer 1: bf16 gather-mean of x (D=32), GEMM 32->64 + relu -> h1b (bf16)
    agg_bf16_kernel<32><<<((size_t)N * 4 + TB - 1) / TB, TB, 0, stream>>>(xb, csr_src,
                                                                          offsets, agg, N);
    gemm_dense_kernel<32, false, false><<<(N + 63) / 64, TB, 0, stream>>>(
        agg, x, nullptr, W1_l, W1_r, b1, h1b, nullptr, nullptr, N, 16);

    // layer 2: bf16 gather-mean of h1b (D=64), GEMM 64->64 + relu + pool
    agg_bf16_kernel<64><<<((size_t)N * 8 + TB - 1) / TB, TB, 0, stream>>>(h1b, csr_src,
                                                                          offsets, agg, N);
    gemm_dense_kernel<64, true, true><<<(N + 63) / 64, TB, 0, stream>>>(
        agg, nullptr, h1b, W2_l, W2_r, b2, nullptr, batch, pool, N, 16);

    final_kernel<<<(G * 2 + TB - 1) / TB, TB, 0, stream>>>(pool, cnt, W_lin, b_lin, out, G);
}

// Round 12
// 443.829 us; speedup vs baseline: 8.4960x; 1.0508x over previous
//
#include <hip/hip_runtime.h>
#include <hip/hip_bf16.h>

// JetGNN: 2-layer SAGEConv(mean) + ReLU + global_mean_pool + Linear(64->2)
// R1: hierarchical scan. R2: bucketed counting-sort CSR build.
// R3: run-flush pool. R4: agg x4 unroll WIN. R5-R8: wave-uniform dense dead end.
// R9: LDS-tiled GEMM WIN. R10: bf16 gather WIN. R11: runtime kIter kills the
//     full-unroll VGPR explosion (240->68, 120->84us) -- but vector GEMM is
//     issue-bound: 64 v_fmac + 8 ds_read_b128 per 8192 FLOP.
// R12: dense -> MFMA 16x16x32_bf16. Per wave: 1 A-frag + 8 B-frag reads feed
//     8 mfma (65K FLOP). Weights double-bf16 (hi+lo residual) => weight error
//     ~2^-16; only feature bf16 error remains. Layouts per m89/m91:
//     A[m=lane&15][k=q*8+j], B[k][n=lane&15] (W rows [o][k]),
//     D col=lane&15,row=q*4+reg. k-step loop trip count RUNTIME (R11 lesson).

#define WS_ALIGN 64
#define EPB 4096          // edges per block in bucket_scatter (256 thr x 16)
#define BSHIFT 10         // 1024 nodes per bucket
#define BNODES 1024

typedef short bf16x8 __attribute__((ext_vector_type(8)));
typedef float f32x4 __attribute__((ext_vector_type(4)));

__device__ inline unsigned short f2bf(float f) {   // RNE f32->bf16 (finite inputs)
    unsigned u = __float_as_uint(f);
    return (unsigned short)((u + 0x7fffu + ((u >> 16) & 1u)) >> 16);
}

__device__ inline float bf2f(unsigned short u) {
    return __uint_as_float((unsigned)u << 16);
}

__device__ inline void acc8(const uint4 u, float* a) {  // 8 bf16 -> fp32 accumulate
    a[0] += __uint_as_float(u.x << 16);
    a[1] += __uint_as_float(u.x & 0xffff0000u);
    a[2] += __uint_as_float(u.y << 16);
    a[3] += __uint_as_float(u.y & 0xffff0000u);
    a[4] += __uint_as_float(u.z << 16);
    a[5] += __uint_as_float(u.z & 0xffff0000u);
    a[6] += __uint_as_float(u.w << 16);
    a[7] += __uint_as_float(u.w & 0xffff0000u);
}

// ---------- pooling counts ----------

__global__ void cnt_kernel(const int* __restrict__ batch, int* __restrict__ cnt, int N) {
    int i = blockIdx.x * blockDim.x + threadIdx.x;
    if (i < N) atomicAdd(&cnt[batch[i]], 1);
}

// ---------- x (f32) -> xb (bf16) ----------

__global__ void cvt_kernel(const float* __restrict__ x, unsigned short* __restrict__ xb,
                           int total4) {
    int i = blockIdx.x * blockDim.x + threadIdx.x;
    if (i >= total4) return;
    const float4 v = reinterpret_cast<const float4*>(x)[i];
    ushort4 o;
    o.x = f2bf(v.x); o.y = f2bf(v.y); o.z = f2bf(v.z); o.w = f2bf(v.w);
    reinterpret_cast<ushort4*>(xb)[i] = o;
}

// ---------- bucketed CSR construction ----------

__global__ __launch_bounds__(256) void bucket_hist_kernel(const int* __restrict__ dst,
                                                          int* __restrict__ bucketCount, int E) {
    __shared__ int hist[256];
    const int t = threadIdx.x;
    hist[t] = 0;
    __syncthreads();
    for (int e = blockIdx.x * blockDim.x + t; e < E; e += gridDim.x * blockDim.x)
        atomicAdd(&hist[dst[e] >> BSHIFT], 1);
    __syncthreads();
    if (hist[t] > 0) atomicAdd(&bucketCount[t], hist[t]);
}

__global__ __launch_bounds__(256) void bucket_scan_kernel(const int* __restrict__ bucketCount,
                                                          int* __restrict__ bucketBase,
                                                          int* __restrict__ bucketCursor,
                                                          int NB, int E) {
    __shared__ int s[256];
    const int t = threadIdx.x;
    int v = (t < NB) ? bucketCount[t] : 0;
    s[t] = v;
    __syncthreads();
    for (int off = 1; off < 256; off <<= 1) {
        int u = (t >= off) ? s[t - off] : 0;
        __syncthreads();
        s[t] += u;
        __syncthreads();
    }
    int excl = s[t] - v;
    if (t < NB) { bucketBase[t] = excl; bucketCursor[t] = excl; }
    if (t == 0) bucketBase[NB] = E;
}

__global__ __launch_bounds__(256) void bucket_scatter_kernel(const int* __restrict__ src,
                                                             const int* __restrict__ dst,
                                                             int* __restrict__ bucketCursor,
                                                             unsigned* __restrict__ bucketData,
                                                             int E, int NB) {
    __shared__ int hist[256];
    __shared__ int cur[256];
    const int t = threadIdx.x;
    hist[t] = 0;
    __syncthreads();
    const int eBase = blockIdx.x * EPB + t;
    int s[16], b[16], dl[16];
#pragma unroll
    for (int j = 0; j < 16; ++j) {
        int e = eBase + j * 256;
        if (e < E) {
            int d = dst[e];
            s[j]  = src[e];
            b[j]  = d >> BSHIFT;
            dl[j] = d & (BNODES - 1);
            atomicAdd(&hist[b[j]], 1);
        } else {
            b[j] = -1;
        }
    }
    __syncthreads();
    if (t < NB && hist[t] > 0) cur[t] = atomicAdd(&bucketCursor[t], hist[t]);
    __syncthreads();
#pragma unroll
    for (int j = 0; j < 16; ++j) {
        if (b[j] >= 0) {
            int pos = atomicAdd(&cur[b[j]], 1);
            bucketData[pos] = ((unsigned)s[j] << BSHIFT) | (unsigned)dl[j];
        }
    }
}

__global__ __launch_bounds__(256) void csr_build_kernel(const unsigned* __restrict__ bucketData,
                                                        const int* __restrict__ bucketBase,
                                                        int* __restrict__ offsets,
                                                        int* __restrict__ csr_src,
                                                        int N, int E, int NB) {
    __shared__ int cnt[BNODES];
    __shared__ int sscan[256];
    __shared__ int cur[BNODES];
    const int t   = threadIdx.x;
    const int bkt = blockIdx.x;
    const int beg = bucketBase[bkt];
    const int end = bucketBase[bkt + 1];
    for (int i = t; i < BNODES; i += 256) cnt[i] = 0;
    __syncthreads();
    for (int k = beg + t; k < end; k += 256)
        atomicAdd(&cnt[bucketData[k] & (BNODES - 1)], 1);
    __syncthreads();
    int local[4];
    int sum = 0;
#pragma unroll
    for (int j = 0; j < 4; ++j) { local[j] = sum; sum += cnt[t * 4 + j]; }
    sscan[t] = sum;
    __syncthreads();
    for (int off = 1; off < 256; off <<= 1) {
        int v = (t >= off) ? sscan[t - off] : 0;
        __syncthreads();
        sscan[t] += v;
        __syncthreads();
    }
    int base = (t > 0) ? sscan[t - 1] : 0;
#pragma unroll
    for (int j = 0; j < 4; ++j) cur[t * 4 + j] = base + local[j];
    __syncthreads();
    for (int i = t; i < BNODES; i += 256) {
        int node = (bkt << BSHIFT) + i;
        if (node <= N) offsets[node] = beg + cur[i];
    }
    if (bkt == NB - 1 && t == 0 && (NB << BSHIFT) == N) offsets[N] = E;
    __syncthreads();
    for (int k = beg + t; k < end; k += 256) {
        unsigned v = bucketData[k];
        int d   = (int)(v & (BNODES - 1));
        int pos = beg + atomicAdd(&cur[d], 1);
        csr_src[pos] = (int)(v >> BSHIFT);
    }
}

// ---------- mean aggregation from bf16 features (fp32 accumulate) ----------

template <int D>
__global__ void agg_bf16_kernel(const unsigned short* __restrict__ featb,
                                const int* __restrict__ csr_src,
                                const int* __restrict__ offsets,
                                float* __restrict__ agg, int N) {
    constexpr int TPN = D / 8;
    int tid  = blockIdx.x * blockDim.x + threadIdx.x;
    int node = tid / TPN;
    int part = tid % TPN;
    if (node >= N) return;
    const int beg = offsets[node];
    const int end = offsets[node + 1];
    const uint4* base = reinterpret_cast<const uint4*>(featb);
    float a[8] = {0.f, 0.f, 0.f, 0.f, 0.f, 0.f, 0.f, 0.f};
    int k = beg;
    for (; k + 4 <= end; k += 4) {
        const int s0 = csr_src[k + 0];
        const int s1 = csr_src[k + 1];
        const int s2 = csr_src[k + 2];
        const int s3 = csr_src[k + 3];
        const uint4 u0 = base[(size_t)s0 * TPN + part];
        const uint4 u1 = base[(size_t)s1 * TPN + part];
        const uint4 u2 = base[(size_t)s2 * TPN + part];
        const uint4 u3 = base[(size_t)s3 * TPN + part];
        acc8(u0, a); acc8(u1, a); acc8(u2, a); acc8(u3, a);
    }
    for (; k < end; ++k) {
        const uint4 u = base[(size_t)csr_src[k] * TPN + part];
        acc8(u, a);
    }
    const float inv = 1.0f / fmaxf((float)(end - beg), 1.0f);
    float4 lo = make_float4(a[0] * inv, a[1] * inv, a[2] * inv, a[3] * inv);
    float4 hi = make_float4(a[4] * inv, a[5] * inv, a[6] * inv, a[7] * inv);
    float* dstp = agg + (size_t)node * D + part * 8;
    *reinterpret_cast<float4*>(dstp)     = lo;
    *reinterpret_cast<float4*>(dstp + 4) = hi;
}

// ---------- dense via MFMA 16x16x32 bf16 ----------
// Block = 64 nodes x 64 outs, 4 waves; wave w owns nodes [w*16, w*16+16).
// A_s[node][k] bf16: k<DIN = bf16(agg row), k>=DIN = xin (bf16 source).
// B (weights) double-bf16: Bh_s + Bl_s rows [o][k] = [Wl[o] | Wr[o]].
// Row stride K+8 bf16 -> frag-read addresses stride 4 mod 32 dwords
// (2-way alias only, free). nSteps (=K/32) is RUNTIME to stop full unroll.

template <int DIN, bool POOL>
__launch_bounds__(256)
__global__ void mfma_dense_kernel(const float* __restrict__ agg,
                                  const unsigned short* __restrict__ xinb,
                                  const float* __restrict__ Wl,
                                  const float* __restrict__ Wr,
                                  const float* __restrict__ bias,
                                  unsigned short* __restrict__ houtb,
                                  const int* __restrict__ batch,
                                  float* __restrict__ pool_sum,
                                  int N, int nSteps) {
    constexpr int K   = 2 * DIN;      // 64 / 128
    constexpr int STR = K + 8;        // 72 / 136 ushorts, rows 16B-aligned
    constexpr int D4  = DIN / 4;
    constexpr int D8  = DIN / 8;
    __shared__ unsigned short A_s[64 * STR];
    __shared__ unsigned short Bh_s[64 * STR];
    __shared__ unsigned short Bl_s[64 * STR];
    const int tid = threadIdx.x;
    const int nodeBase = blockIdx.x * 64;

    // A: agg (f32 -> bf16) into k [0, DIN)
    for (int i = tid; i < 64 * D4; i += 256) {
        const int node = i / D4, c4 = i % D4;
        const int n = min(nodeBase + node, N - 1);
        const float4 v = *reinterpret_cast<const float4*>(agg + (size_t)n * DIN + c4 * 4);
        ushort4 u;
        u.x = f2bf(v.x); u.y = f2bf(v.y); u.z = f2bf(v.z); u.w = f2bf(v.w);
        *reinterpret_cast<ushort4*>(&A_s[node * STR + c4 * 4]) = u;
    }
    // A: xin (bf16 source) into k [DIN, 2*DIN)
    for (int i = tid; i < 64 * D8; i += 256) {
        const int node = i / D8, q = i % D8;
        const int n = min(nodeBase + node, N - 1);
        const uint4 u = *reinterpret_cast<const uint4*>(xinb + (size_t)n * DIN + q * 8);
        *reinterpret_cast<uint4*>(&A_s[node * STR + DIN + q * 8]) = u;
    }
    // B: weights double-bf16; row o = [Wl[o] | Wr[o]]
    for (int i = tid; i < 64 * D4 * 2; i += 256) {
        const int half = i / (64 * D4);
        const int j = i % (64 * D4);
        const int o = j / D4, c4 = j % D4;
        const float* W = half ? Wr : Wl;
        const float4 v = *reinterpret_cast<const float4*>(W + (size_t)o * DIN + c4 * 4);
        ushort4 hi, lo;
        hi.x = f2bf(v.x); hi.y = f2bf(v.y); hi.z = f2bf(v.z); hi.w = f2bf(v.w);
        lo.x = f2bf(v.x - bf2f(hi.x));
        lo.y = f2bf(v.y - bf2f(hi.y));
        lo.z = f2bf(v.z - bf2f(hi.z));
        lo.w = f2bf(v.w - bf2f(hi.w));
        *reinterpret_cast<ushort4*>(&Bh_s[o * STR + half * DIN + c4 * 4]) = hi;
        *reinterpret_cast<ushort4*>(&Bl_s[o * STR + half * DIN + c4 * 4]) = lo;
    }
    __syncthreads();

    const int lane = tid & 63;
    const int wave = tid >> 6;
    const int lr = lane & 15;        // A: m (node); B: n (out); D: col (out)
    const int q  = lane >> 4;        // frag k-quad; D row group
    f32x4 acc[4];
#pragma unroll
    for (int t = 0; t < 4; ++t) {
        const float b = bias[t * 16 + lr];
        acc[t] = (f32x4){b, b, b, b};
    }
    const unsigned short* Arow = &A_s[(wave * 16 + lr) * STR + q * 8];
    for (int s = 0; s < nSteps; ++s) {    // runtime: no full unroll
        const bf16x8 af = *reinterpret_cast<const bf16x8*>(Arow + s * 32);
#pragma unroll
        for (int t = 0; t < 4; ++t) {
            const int boff = (t * 16 + lr) * STR + s * 32 + q * 8;
            const bf16x8 bh = *reinterpret_cast<const bf16x8*>(&Bh_s[boff]);
            const bf16x8 bl = *reinterpret_cast<const bf16x8*>(&Bl_s[boff]);
            acc[t] = __builtin_amdgcn_mfma_f32_16x16x32_bf16(af, bh, acc[t], 0, 0, 0);
            acc[t] = __builtin_amdgcn_mfma_f32_16x16x32_bf16(af, bl, acc[t], 0, 0, 0);
        }
    }

    // D layout: row(node local 16) = q*4 + reg, col(out) = t*16 + lr
    if (POOL) {
        float ag[4] = {0.f, 0.f, 0.f, 0.f};
        int gcur = -1;
        for (int reg = 0; reg < 4; ++reg) {
            const int n = nodeBase + wave * 16 + q * 4 + reg;
            if (n >= N) break;
            const int g = batch[n];              // sorted
            if (g != gcur) {
                if (gcur >= 0) {
#pragma unroll
                    for (int t = 0; t < 4; ++t)
                        atomicAdd(&pool_sum[(size_t)gcur * 64 + t * 16 + lr], ag[t]);
                }
                gcur = g;
                ag[0] = ag[1] = ag[2] = ag[3] = 0.f;
            }
#pragma unroll
            for (int t = 0; t < 4; ++t)
                ag[t] += fmaxf(acc[t][reg], 0.0f);
        }
        if (gcur >= 0) {
#pragma unroll
            for (int t = 0; t < 4; ++t)
                atomicAdd(&pool_sum[(size_t)gcur * 64 + t * 16 + lr], ag[t]);
        }
    } else {
        for (int reg = 0; reg < 4; ++reg) {
            const int n = nodeBase + wave * 16 + q * 4 + reg;
            if (n >= N) break;
#pragma unroll
            for (int t = 0; t < 4; ++t)
                houtb[(size_t)n * 64 + t * 16 + lr] = f2bf(fmaxf(acc[t][reg], 0.0f));
        }
    }
}

// ---------- head ----------

__global__ void final_kernel(const float* __restrict__ pool_sum,
                             const int* __restrict__ cnt,
                             const float* __restrict__ W_lin,
                             const float* __restrict__ b_lin,
                             float* __restrict__ out, int G) {
    int t = blockIdx.x * blockDim.x + threadIdx.x;
    if (t >= G * 2) return;
    int g = t >> 1, o = t & 1;
    float inv = 1.0f / fmaxf((float)cnt[g], 1.0f);
    float acc = b_lin[o];
#pragma unroll
    for (int c = 0; c < 64; ++c)
        acc = fmaf(pool_sum[(size_t)g * 64 + c] * inv, W_lin[o * 64 + c], acc);
    out[t] = acc;
}

extern "C" void kernel_launch(void* const* d_in, const int* in_sizes, int n_in,
                              void* d_out, int out_size, void* d_ws, size_t ws_size,
                              hipStream_t stream) {
    const float* x     = (const float*)d_in[0];
    const int*   ei    = (const int*)d_in[1];
    const int*   batch = (const int*)d_in[2];
    const float* W1_l  = (const float*)d_in[3];
    const float* b1    = (const float*)d_in[4];
    const float* W1_r  = (const float*)d_in[5];
    const float* W2_l  = (const float*)d_in[6];
    const float* b2    = (const float*)d_in[7];
    const float* W2_r  = (const float*)d_in[8];
    const float* W_lin = (const float*)d_in[9];
    const float* b_lin = (const float*)d_in[10];

    const int N = in_sizes[0] / 32;
    const int E = in_sizes[1] / 2;
    const int G = out_size / 2;
    const int* src = ei;
    const int* dst = ei + E;
    const int NB = (N + BNODES - 1) >> BSHIFT;   // 196 for N=200000

    char* p = (char*)d_ws;
    auto carve = [&](size_t bytes) -> void* {
        void* r = (void*)p;
        p += (bytes + (WS_ALIGN - 1)) / WS_ALIGN * WS_ALIGN;
        return r;
    };
    int*            bucketCount  = (int*)carve(256 * 4);
    int*            bucketBase   = (int*)carve(257 * 4);
    int*            bucketCursor = (int*)carve(256 * 4);
    unsigned*       bucketData   = (unsigned*)carve((size_t)E * 4);
    int*            offsets      = (int*)carve((size_t)(N + 1) * 4);
    int*            csr_src      = (int*)carve((size_t)E * 4);
    float*          agg          = (float*)carve((size_t)N * 64 * 4);
    unsigned short* xb           = (unsigned short*)carve((size_t)N * 32 * 2);
    unsigned short* h1b          = (unsigned short*)carve((size_t)N * 64 * 2);
    float*          pool         = (float*)carve((size_t)G * 64 * 4);
    int*            cnt          = (int*)carve((size_t)G * 4);
    float*          out          = (float*)d_out;

    hipMemsetAsync(bucketCount, 0, 256 * 4, stream);
    hipMemsetAsync(pool, 0, (size_t)G * 64 * 4, stream);
    hipMemsetAsync(cnt, 0, (size_t)G * 4, stream);

    const int TB = 256;
    cnt_kernel<<<(N + TB - 1) / TB, TB, 0, stream>>>(batch, cnt, N);
    cvt_kernel<<<((N * 32 / 4) + TB - 1) / TB, TB, 0, stream>>>(x, xb, N * 32 / 4);
    bucket_hist_kernel<<<1024, TB, 0, stream>>>(dst, bucketCount, E);
    bucket_scan_kernel<<<1, TB, 0, stream>>>(bucketCount, bucketBase, bucketCursor, NB, E);
    bucket_scatter_kernel<<<(E + EPB - 1) / EPB, TB, 0, stream>>>(src, dst, bucketCursor,
                                                                  bucketData, E, NB);
    csr_build_kernel<<<NB, TB, 0, stream>>>(bucketData, bucketBase, offsets, csr_src, N, E, NB);

    // layer 1: bf16 gather-mean of x (D=32), MFMA 32->64 + relu -> h1b (bf16)
    agg_bf16_kernel<32><<<((size_t)N * 4 + TB - 1) / TB, TB, 0, stream>>>(xb, csr_src,
                                                                          offsets, agg, N);
    mfma_dense_kernel<32, false><<<(N + 63) / 64, TB, 0, stream>>>(
        agg, xb, W1_l, W1_r, b1, h1b, nullptr, nullptr, N, 2);

    // layer 2: bf16 gather-mean of h1b (D=64), MFMA 64->64 + relu + pool
    agg_bf16_kernel<64><<<((size_t)N * 8 + TB - 1) / TB, TB, 0, stream>>>(h1b, csr_src,
                                                                          offsets, agg, N);
    mfma_dense_kernel<64, true><<<(N + 63) / 64, TB, 0, stream>>>(
        agg, h1b, W2_l, W2_r, b2, nullptr, batch, pool, N, 4);

    final_kernel<<<(G * 2 + TB - 1) / TB, TB, 0, stream>>>(pool, cnt, W_lin, b_lin, out, G);
}

// Round 13
// 425.669 us; speedup vs baseline: 8.8584x; 1.0427x over previous
//
#include <hip/hip_runtime.h>
#include <hip/hip_bf16.h>

// JetGNN: 2-layer SAGEConv(mean) + ReLU + global_mean_pool + Linear(64->2)
// R1: hierarchical scan. R2: bucketed counting-sort CSR build.
// R3: run-flush pool. R4: agg x4 unroll WIN. R5-R8: wave-uniform dense dead end.
// R9: LDS-tiled GEMM WIN. R10: bf16 gather WIN. R11: runtime kIter (VGPR fix).
// R12: dense -> MFMA 16x16x32_bf16, double-bf16 weights (hi+lo) WIN.
// R13: agg outputs bf16 directly (the mfma staging rounded to bf16 anyway --
//      identical numerics, kills 50MB fp32 write + 50MB read); gather unroll
//      4->8 (VGPR 28 -> ~60, was latency-limited at 46% HBM).

#define WS_ALIGN 64
#define EPB 4096          // edges per block in bucket_scatter (256 thr x 16)
#define BSHIFT 10         // 1024 nodes per bucket
#define BNODES 1024

typedef short bf16x8 __attribute__((ext_vector_type(8)));
typedef float f32x4 __attribute__((ext_vector_type(4)));

__device__ inline unsigned short f2bf(float f) {   // RNE f32->bf16 (finite inputs)
    unsigned u = __float_as_uint(f);
    return (unsigned short)((u + 0x7fffu + ((u >> 16) & 1u)) >> 16);
}

__device__ inline float bf2f(unsigned short u) {
    return __uint_as_float((unsigned)u << 16);
}

__device__ inline void acc8(const uint4 u, float* a) {  // 8 bf16 -> fp32 accumulate
    a[0] += __uint_as_float(u.x << 16);
    a[1] += __uint_as_float(u.x & 0xffff0000u);
    a[2] += __uint_as_float(u.y << 16);
    a[3] += __uint_as_float(u.y & 0xffff0000u);
    a[4] += __uint_as_float(u.z << 16);
    a[5] += __uint_as_float(u.z & 0xffff0000u);
    a[6] += __uint_as_float(u.w << 16);
    a[7] += __uint_as_float(u.w & 0xffff0000u);
}

// ---------- pooling counts ----------

__global__ void cnt_kernel(const int* __restrict__ batch, int* __restrict__ cnt, int N) {
    int i = blockIdx.x * blockDim.x + threadIdx.x;
    if (i < N) atomicAdd(&cnt[batch[i]], 1);
}

// ---------- x (f32) -> xb (bf16) ----------

__global__ void cvt_kernel(const float* __restrict__ x, unsigned short* __restrict__ xb,
                           int total4) {
    int i = blockIdx.x * blockDim.x + threadIdx.x;
    if (i >= total4) return;
    const float4 v = reinterpret_cast<const float4*>(x)[i];
    ushort4 o;
    o.x = f2bf(v.x); o.y = f2bf(v.y); o.z = f2bf(v.z); o.w = f2bf(v.w);
    reinterpret_cast<ushort4*>(xb)[i] = o;
}

// ---------- bucketed CSR construction ----------

__global__ __launch_bounds__(256) void bucket_hist_kernel(const int* __restrict__ dst,
                                                          int* __restrict__ bucketCount, int E) {
    __shared__ int hist[256];
    const int t = threadIdx.x;
    hist[t] = 0;
    __syncthreads();
    for (int e = blockIdx.x * blockDim.x + t; e < E; e += gridDim.x * blockDim.x)
        atomicAdd(&hist[dst[e] >> BSHIFT], 1);
    __syncthreads();
    if (hist[t] > 0) atomicAdd(&bucketCount[t], hist[t]);
}

__global__ __launch_bounds__(256) void bucket_scan_kernel(const int* __restrict__ bucketCount,
                                                          int* __restrict__ bucketBase,
                                                          int* __restrict__ bucketCursor,
                                                          int NB, int E) {
    __shared__ int s[256];
    const int t = threadIdx.x;
    int v = (t < NB) ? bucketCount[t] : 0;
    s[t] = v;
    __syncthreads();
    for (int off = 1; off < 256; off <<= 1) {
        int u = (t >= off) ? s[t - off] : 0;
        __syncthreads();
        s[t] += u;
        __syncthreads();
    }
    int excl = s[t] - v;
    if (t < NB) { bucketBase[t] = excl; bucketCursor[t] = excl; }
    if (t == 0) bucketBase[NB] = E;
}

__global__ __launch_bounds__(256) void bucket_scatter_kernel(const int* __restrict__ src,
                                                             const int* __restrict__ dst,
                                                             int* __restrict__ bucketCursor,
                                                             unsigned* __restrict__ bucketData,
                                                             int E, int NB) {
    __shared__ int hist[256];
    __shared__ int cur[256];
    const int t = threadIdx.x;
    hist[t] = 0;
    __syncthreads();
    const int eBase = blockIdx.x * EPB + t;
    int s[16], b[16], dl[16];
#pragma unroll
    for (int j = 0; j < 16; ++j) {
        int e = eBase + j * 256;
        if (e < E) {
            int d = dst[e];
            s[j]  = src[e];
            b[j]  = d >> BSHIFT;
            dl[j] = d & (BNODES - 1);
            atomicAdd(&hist[b[j]], 1);
        } else {
            b[j] = -1;
        }
    }
    __syncthreads();
    if (t < NB && hist[t] > 0) cur[t] = atomicAdd(&bucketCursor[t], hist[t]);
    __syncthreads();
#pragma unroll
    for (int j = 0; j < 16; ++j) {
        if (b[j] >= 0) {
            int pos = atomicAdd(&cur[b[j]], 1);
            bucketData[pos] = ((unsigned)s[j] << BSHIFT) | (unsigned)dl[j];
        }
    }
}

__global__ __launch_bounds__(256) void csr_build_kernel(const unsigned* __restrict__ bucketData,
                                                        const int* __restrict__ bucketBase,
                                                        int* __restrict__ offsets,
                                                        int* __restrict__ csr_src,
                                                        int N, int E, int NB) {
    __shared__ int cnt[BNODES];
    __shared__ int sscan[256];
    __shared__ int cur[BNODES];
    const int t   = threadIdx.x;
    const int bkt = blockIdx.x;
    const int beg = bucketBase[bkt];
    const int end = bucketBase[bkt + 1];
    for (int i = t; i < BNODES; i += 256) cnt[i] = 0;
    __syncthreads();
    for (int k = beg + t; k < end; k += 256)
        atomicAdd(&cnt[bucketData[k] & (BNODES - 1)], 1);
    __syncthreads();
    int local[4];
    int sum = 0;
#pragma unroll
    for (int j = 0; j < 4; ++j) { local[j] = sum; sum += cnt[t * 4 + j]; }
    sscan[t] = sum;
    __syncthreads();
    for (int off = 1; off < 256; off <<= 1) {
        int v = (t >= off) ? sscan[t - off] : 0;
        __syncthreads();
        sscan[t] += v;
        __syncthreads();
    }
    int base = (t > 0) ? sscan[t - 1] : 0;
#pragma unroll
    for (int j = 0; j < 4; ++j) cur[t * 4 + j] = base + local[j];
    __syncthreads();
    for (int i = t; i < BNODES; i += 256) {
        int node = (bkt << BSHIFT) + i;
        if (node <= N) offsets[node] = beg + cur[i];
    }
    if (bkt == NB - 1 && t == 0 && (NB << BSHIFT) == N) offsets[N] = E;
    __syncthreads();
    for (int k = beg + t; k < end; k += 256) {
        unsigned v = bucketData[k];
        int d   = (int)(v & (BNODES - 1));
        int pos = beg + atomicAdd(&cur[d], 1);
        csr_src[pos] = (int)(v >> BSHIFT);
    }
}

// ---------- mean aggregation bf16 -> bf16 (fp32 accumulate) ----------
// D/8 lanes per node; 8 gathers in flight (R13); output bf16 (same rounding
// point the mfma staging used -- no new error, half the bytes).

template <int D>
__global__ void agg_bf16_kernel(const unsigned short* __restrict__ featb,
                                const int* __restrict__ csr_src,
                                const int* __restrict__ offsets,
                                unsigned short* __restrict__ aggb, int N) {
    constexpr int TPN = D / 8;
    int tid  = blockIdx.x * blockDim.x + threadIdx.x;
    int node = tid / TPN;
    int part = tid % TPN;
    if (node >= N) return;
    const int beg = offsets[node];
    const int end = offsets[node + 1];
    const uint4* base = reinterpret_cast<const uint4*>(featb);
    float a[8] = {0.f, 0.f, 0.f, 0.f, 0.f, 0.f, 0.f, 0.f};
    int k = beg;
    for (; k + 8 <= end; k += 8) {
        int s[8];
#pragma unroll
        for (int j = 0; j < 8; ++j) s[j] = csr_src[k + j];
        uint4 u[8];
#pragma unroll
        for (int j = 0; j < 8; ++j) u[j] = base[(size_t)s[j] * TPN + part];
#pragma unroll
        for (int j = 0; j < 8; ++j) acc8(u[j], a);
    }
    for (; k + 4 <= end; k += 4) {
        const int s0 = csr_src[k + 0];
        const int s1 = csr_src[k + 1];
        const int s2 = csr_src[k + 2];
        const int s3 = csr_src[k + 3];
        const uint4 u0 = base[(size_t)s0 * TPN + part];
        const uint4 u1 = base[(size_t)s1 * TPN + part];
        const uint4 u2 = base[(size_t)s2 * TPN + part];
        const uint4 u3 = base[(size_t)s3 * TPN + part];
        acc8(u0, a); acc8(u1, a); acc8(u2, a); acc8(u3, a);
    }
    for (; k < end; ++k) {
        const uint4 u = base[(size_t)csr_src[k] * TPN + part];
        acc8(u, a);
    }
    const float inv = 1.0f / fmaxf((float)(end - beg), 1.0f);
    ushort4 lo, hi;
    lo.x = f2bf(a[0] * inv); lo.y = f2bf(a[1] * inv);
    lo.z = f2bf(a[2] * inv); lo.w = f2bf(a[3] * inv);
    hi.x = f2bf(a[4] * inv); hi.y = f2bf(a[5] * inv);
    hi.z = f2bf(a[6] * inv); hi.w = f2bf(a[7] * inv);
    unsigned short* dstp = aggb + (size_t)node * D + part * 8;
    *reinterpret_cast<ushort4*>(dstp)     = lo;
    *reinterpret_cast<ushort4*>(dstp + 4) = hi;
}

// ---------- dense via MFMA 16x16x32 bf16 ----------
// Block = 64 nodes x 64 outs, 4 waves; wave w owns nodes [w*16, w*16+16).
// A_s[node][k] bf16: k<DIN = aggb row, k>=DIN = xin row (both bf16 sources).
// B (weights) double-bf16: Bh_s + Bl_s rows [o][k] = [Wl[o] | Wr[o]].
// Row stride K+8 -> only free 2-way bank aliasing. nSteps RUNTIME (R11).

template <int DIN, bool POOL>
__launch_bounds__(256)
__global__ void mfma_dense_kernel(const unsigned short* __restrict__ aggb,
                                  const unsigned short* __restrict__ xinb,
                                  const float* __restrict__ Wl,
                                  const float* __restrict__ Wr,
                                  const float* __restrict__ bias,
                                  unsigned short* __restrict__ houtb,
                                  const int* __restrict__ batch,
                                  float* __restrict__ pool_sum,
                                  int N, int nSteps) {
    constexpr int K   = 2 * DIN;      // 64 / 128
    constexpr int STR = K + 8;        // 72 / 136 ushorts, rows 16B-aligned
    constexpr int D4  = DIN / 4;
    constexpr int D8  = DIN / 8;
    __shared__ unsigned short A_s[64 * STR];
    __shared__ unsigned short Bh_s[64 * STR];
    __shared__ unsigned short Bl_s[64 * STR];
    const int tid = threadIdx.x;
    const int nodeBase = blockIdx.x * 64;

    // A: aggb into k [0, DIN), xinb into k [DIN, 2*DIN) -- both bf16 copies
    for (int i = tid; i < 64 * D8 * 2; i += 256) {
        const int half = i / (64 * D8);
        const int j = i % (64 * D8);
        const int node = j / D8, q = j % D8;
        const int n = min(nodeBase + node, N - 1);
        const unsigned short* srcp = half ? xinb : aggb;
        const uint4 u = *reinterpret_cast<const uint4*>(srcp + (size_t)n * DIN + q * 8);
        *reinterpret_cast<uint4*>(&A_s[node * STR + half * DIN + q * 8]) = u;
    }
    // B: weights double-bf16; row o = [Wl[o] | Wr[o]]
    for (int i = tid; i < 64 * D4 * 2; i += 256) {
        const int half = i / (64 * D4);
        const int j = i % (64 * D4);
        const int o = j / D4, c4 = j % D4;
        const float* W = half ? Wr : Wl;
        const float4 v = *reinterpret_cast<const float4*>(W + (size_t)o * DIN + c4 * 4);
        ushort4 hi, lo;
        hi.x = f2bf(v.x); hi.y = f2bf(v.y); hi.z = f2bf(v.z); hi.w = f2bf(v.w);
        lo.x = f2bf(v.x - bf2f(hi.x));
        lo.y = f2bf(v.y - bf2f(hi.y));
        lo.z = f2bf(v.z - bf2f(hi.z));
        lo.w = f2bf(v.w - bf2f(hi.w));
        *reinterpret_cast<ushort4*>(&Bh_s[o * STR + half * DIN + c4 * 4]) = hi;
        *reinterpret_cast<ushort4*>(&Bl_s[o * STR + half * DIN + c4 * 4]) = lo;
    }
    __syncthreads();

    const int lane = tid & 63;
    const int wave = tid >> 6;
    const int lr = lane & 15;        // A: m (node); B: n (out); D: col (out)
    const int q  = lane >> 4;        // frag k-quad; D row group
    f32x4 acc[4];
#pragma unroll
    for (int t = 0; t < 4; ++t) {
        const float b = bias[t * 16 + lr];
        acc[t] = (f32x4){b, b, b, b};
    }
    const unsigned short* Arow = &A_s[(wave * 16 + lr) * STR + q * 8];
    for (int s = 0; s < nSteps; ++s) {    // runtime: no full unroll
        const bf16x8 af = *reinterpret_cast<const bf16x8*>(Arow + s * 32);
#pragma unroll
        for (int t = 0; t < 4; ++t) {
            const int boff = (t * 16 + lr) * STR + s * 32 + q * 8;
            const bf16x8 bh = *reinterpret_cast<const bf16x8*>(&Bh_s[boff]);
            const bf16x8 bl = *reinterpret_cast<const bf16x8*>(&Bl_s[boff]);
            acc[t] = __builtin_amdgcn_mfma_f32_16x16x32_bf16(af, bh, acc[t], 0, 0, 0);
            acc[t] = __builtin_amdgcn_mfma_f32_16x16x32_bf16(af, bl, acc[t], 0, 0, 0);
        }
    }

    // D layout: row(node local 16) = q*4 + reg, col(out) = t*16 + lr
    if (POOL) {
        float ag[4] = {0.f, 0.f, 0.f, 0.f};
        int gcur = -1;
        for (int reg = 0; reg < 4; ++reg) {
            const int n = nodeBase + wave * 16 + q * 4 + reg;
            if (n >= N) break;
            const int g = batch[n];              // sorted
            if (g != gcur) {
                if (gcur >= 0) {
#pragma unroll
                    for (int t = 0; t < 4; ++t)
                        atomicAdd(&pool_sum[(size_t)gcur * 64 + t * 16 + lr], ag[t]);
                }
                gcur = g;
                ag[0] = ag[1] = ag[2] = ag[3] = 0.f;
            }
#pragma unroll
            for (int t = 0; t < 4; ++t)
                ag[t] += fmaxf(acc[t][reg], 0.0f);
        }
        if (gcur >= 0) {
#pragma unroll
            for (int t = 0; t < 4; ++t)
                atomicAdd(&pool_sum[(size_t)gcur * 64 + t * 16 + lr], ag[t]);
        }
    } else {
        for (int reg = 0; reg < 4; ++reg) {
            const int n = nodeBase + wave * 16 + q * 4 + reg;
            if (n >= N) break;
#pragma unroll
            for (int t = 0; t < 4; ++t)
                houtb[(size_t)n * 64 + t * 16 + lr] = f2bf(fmaxf(acc[t][reg], 0.0f));
        }
    }
}

// ---------- head ----------

__global__ void final_kernel(const float* __restrict__ pool_sum,
                             const int* __restrict__ cnt,
                             const float* __restrict__ W_lin,
                             const float* __restrict__ b_lin,
                             float* __restrict__ out, int G) {
    int t = blockIdx.x * blockDim.x + threadIdx.x;
    if (t >= G * 2) return;
    int g = t >> 1, o = t & 1;
    float inv = 1.0f / fmaxf((float)cnt[g], 1.0f);
    float acc = b_lin[o];
#pragma unroll
    for (int c = 0; c < 64; ++c)
        acc = fmaf(pool_sum[(size_t)g * 64 + c] * inv, W_lin[o * 64 + c], acc);
    out[t] = acc;
}

extern "C" void kernel_launch(void* const* d_in, const int* in_sizes, int n_in,
                              void* d_out, int out_size, void* d_ws, size_t ws_size,
                              hipStream_t stream) {
    const float* x     = (const float*)d_in[0];
    const int*   ei    = (const int*)d_in[1];
    const int*   batch = (const int*)d_in[2];
    const float* W1_l  = (const float*)d_in[3];
    const float* b1    = (const float*)d_in[4];
    const float* W1_r  = (const float*)d_in[5];
    const float* W2_l  = (const float*)d_in[6];
    const float* b2    = (const float*)d_in[7];
    const float* W2_r  = (const float*)d_in[8];
    const float* W_lin = (const float*)d_in[9];
    const float* b_lin = (const float*)d_in[10];

    const int N = in_sizes[0] / 32;
    const int E = in_sizes[1] / 2;
    const int G = out_size / 2;
    const int* src = ei;
    const int* dst = ei + E;
    const int NB = (N + BNODES - 1) >> BSHIFT;   // 196 for N=200000

    char* p = (char*)d_ws;
    auto carve = [&](size_t bytes) -> void* {
        void* r = (void*)p;
        p += (bytes + (WS_ALIGN - 1)) / WS_ALIGN * WS_ALIGN;
        return r;
    };
    int*            bucketCount  = (int*)carve(256 * 4);
    int*            bucketBase   = (int*)carve(257 * 4);
    int*            bucketCursor = (int*)carve(256 * 4);
    unsigned*       bucketData   = (unsigned*)carve((size_t)E * 4);
    int*            offsets      = (int*)carve((size_t)(N + 1) * 4);
    int*            csr_src      = (int*)carve((size_t)E * 4);
    unsigned short* aggb         = (unsigned short*)carve((size_t)N * 64 * 2);
    unsigned short* xb           = (unsigned short*)carve((size_t)N * 32 * 2);
    unsigned short* h1b          = (unsigned short*)carve((size_t)N * 64 * 2);
    float*          pool         = (float*)carve((size_t)G * 64 * 4);
    int*            cnt          = (int*)carve((size_t)G * 4);
    float*          out          = (float*)d_out;

    hipMemsetAsync(bucketCount, 0, 256 * 4, stream);
    hipMemsetAsync(pool, 0, (size_t)G * 64 * 4, stream);
    hipMemsetAsync(cnt, 0, (size_t)G * 4, stream);

    const int TB = 256;
    cnt_kernel<<<(N + TB - 1) / TB, TB, 0, stream>>>(batch, cnt, N);
    cvt_kernel<<<((N * 32 / 4) + TB - 1) / TB, TB, 0, stream>>>(x, xb, N * 32 / 4);
    bucket_hist_kernel<<<1024, TB, 0, stream>>>(dst, bucketCount, E);
    bucket_scan_kernel<<<1, TB, 0, stream>>>(bucketCount, bucketBase, bucketCursor, NB, E);
    bucket_scatter_kernel<<<(E + EPB - 1) / EPB, TB, 0, stream>>>(src, dst, bucketCursor,
                                                                  bucketData, E, NB);
    csr_build_kernel<<<NB, TB, 0, stream>>>(bucketData, bucketBase, offsets, csr_src, N, E, NB);

    // layer 1: bf16 gather-mean of x (D=32) -> aggb, MFMA 32->64 + relu -> h1b
    agg_bf16_kernel<32><<<((size_t)N * 4 + TB - 1) / TB, TB, 0, stream>>>(xb, csr_src,
                                                                          offsets, aggb, N);
    mfma_dense_kernel<32, false><<<(N + 63) / 64, TB, 0, stream>>>(
        aggb, xb, W1_l, W1_r, b1, h1b, nullptr, nullptr, N, 2);

    // layer 2: bf16 gather-mean of h1b (D=64) -> aggb, MFMA 64->64 + relu + pool
    agg_bf16_kernel<64><<<((size_t)N * 8 + TB - 1) / TB, TB, 0, stream>>>(h1b, csr_src,
                                                                          offsets, aggb, N);
    mfma_dense_kernel<64, true><<<(N + 63) / 64, TB, 0, stream>>>(
        aggb, h1b, W2_l, W2_r, b2, nullptr, batch, pool, N, 4);

    final_kernel<<<(G * 2 + TB - 1) / TB, TB, 0, stream>>>(pool, cnt, W_lin, b_lin, out, G);
}

// Round 14
// 420.241 us; speedup vs baseline: 8.9728x; 1.0129x over previous
//
#include <hip/hip_runtime.h>
#include <hip/hip_bf16.h>

// JetGNN: 2-layer SAGEConv(mean) + ReLU + global_mean_pool + Linear(64->2)
// R1: hierarchical scan. R2: bucketed counting-sort CSR build.
// R3: run-flush pool. R4: agg unroll WIN. R5-R8: wave-uniform dense dead end.
// R9: LDS-tiled GEMM WIN. R10: bf16 gather WIN. R11: runtime kIter (VGPR fix).
// R12: MFMA 16x16x32_bf16 + double-bf16 weights WIN. R13: agg->bf16 out WIN.
//      Gather FETCH ~182MB is the STRUCTURAL floor (random 16-nbr sampling
//      covers ~86% of the feature array per XCD; fp8 would blow error budget).
// R14: fuse gather-mean INTO mfma A-staging: aggb buffer + 2 agg kernels gone
//      (~75MB round-trip + 2 launches). Identical numerics (same fp32
//      accumulate, same single bf16 rounding point).

#define WS_ALIGN 64
#define EPB 4096          // edges per block in bucket_scatter (256 thr x 16)
#define BSHIFT 10         // 1024 nodes per bucket
#define BNODES 1024

typedef short bf16x8 __attribute__((ext_vector_type(8)));
typedef float f32x4 __attribute__((ext_vector_type(4)));

__device__ inline unsigned short f2bf(float f) {   // RNE f32->bf16 (finite inputs)
    unsigned u = __float_as_uint(f);
    return (unsigned short)((u + 0x7fffu + ((u >> 16) & 1u)) >> 16);
}

__device__ inline float bf2f(unsigned short u) {
    return __uint_as_float((unsigned)u << 16);
}

__device__ inline void acc8(const uint4 u, float* a) {  // 8 bf16 -> fp32 accumulate
    a[0] += __uint_as_float(u.x << 16);
    a[1] += __uint_as_float(u.x & 0xffff0000u);
    a[2] += __uint_as_float(u.y << 16);
    a[3] += __uint_as_float(u.y & 0xffff0000u);
    a[4] += __uint_as_float(u.z << 16);
    a[5] += __uint_as_float(u.z & 0xffff0000u);
    a[6] += __uint_as_float(u.w << 16);
    a[7] += __uint_as_float(u.w & 0xffff0000u);
}

// ---------- pooling counts ----------

__global__ void cnt_kernel(const int* __restrict__ batch, int* __restrict__ cnt, int N) {
    int i = blockIdx.x * blockDim.x + threadIdx.x;
    if (i < N) atomicAdd(&cnt[batch[i]], 1);
}

// ---------- x (f32) -> xb (bf16) ----------

__global__ void cvt_kernel(const float* __restrict__ x, unsigned short* __restrict__ xb,
                           int total4) {
    int i = blockIdx.x * blockDim.x + threadIdx.x;
    if (i >= total4) return;
    const float4 v = reinterpret_cast<const float4*>(x)[i];
    ushort4 o;
    o.x = f2bf(v.x); o.y = f2bf(v.y); o.z = f2bf(v.z); o.w = f2bf(v.w);
    reinterpret_cast<ushort4*>(xb)[i] = o;
}

// ---------- bucketed CSR construction ----------

__global__ __launch_bounds__(256) void bucket_hist_kernel(const int* __restrict__ dst,
                                                          int* __restrict__ bucketCount, int E) {
    __shared__ int hist[256];
    const int t = threadIdx.x;
    hist[t] = 0;
    __syncthreads();
    for (int e = blockIdx.x * blockDim.x + t; e < E; e += gridDim.x * blockDim.x)
        atomicAdd(&hist[dst[e] >> BSHIFT], 1);
    __syncthreads();
    if (hist[t] > 0) atomicAdd(&bucketCount[t], hist[t]);
}

__global__ __launch_bounds__(256) void bucket_scan_kernel(const int* __restrict__ bucketCount,
                                                          int* __restrict__ bucketBase,
                                                          int* __restrict__ bucketCursor,
                                                          int NB, int E) {
    __shared__ int s[256];
    const int t = threadIdx.x;
    int v = (t < NB) ? bucketCount[t] : 0;
    s[t] = v;
    __syncthreads();
    for (int off = 1; off < 256; off <<= 1) {
        int u = (t >= off) ? s[t - off] : 0;
        __syncthreads();
        s[t] += u;
        __syncthreads();
    }
    int excl = s[t] - v;
    if (t < NB) { bucketBase[t] = excl; bucketCursor[t] = excl; }
    if (t == 0) bucketBase[NB] = E;
}

__global__ __launch_bounds__(256) void bucket_scatter_kernel(const int* __restrict__ src,
                                                             const int* __restrict__ dst,
                                                             int* __restrict__ bucketCursor,
                                                             unsigned* __restrict__ bucketData,
                                                             int E, int NB) {
    __shared__ int hist[256];
    __shared__ int cur[256];
    const int t = threadIdx.x;
    hist[t] = 0;
    __syncthreads();
    const int eBase = blockIdx.x * EPB + t;
    int s[16], b[16], dl[16];
#pragma unroll
    for (int j = 0; j < 16; ++j) {
        int e = eBase + j * 256;
        if (e < E) {
            int d = dst[e];
            s[j]  = src[e];
            b[j]  = d >> BSHIFT;
            dl[j] = d & (BNODES - 1);
            atomicAdd(&hist[b[j]], 1);
        } else {
            b[j] = -1;
        }
    }
    __syncthreads();
    if (t < NB && hist[t] > 0) cur[t] = atomicAdd(&bucketCursor[t], hist[t]);
    __syncthreads();
#pragma unroll
    for (int j = 0; j < 16; ++j) {
        if (b[j] >= 0) {
            int pos = atomicAdd(&cur[b[j]], 1);
            bucketData[pos] = ((unsigned)s[j] << BSHIFT) | (unsigned)dl[j];
        }
    }
}

__global__ __launch_bounds__(256) void csr_build_kernel(const unsigned* __restrict__ bucketData,
                                                        const int* __restrict__ bucketBase,
                                                        int* __restrict__ offsets,
                                                        int* __restrict__ csr_src,
                                                        int N, int E, int NB) {
    __shared__ int cnt[BNODES];
    __shared__ int sscan[256];
    __shared__ int cur[BNODES];
    const int t   = threadIdx.x;
    const int bkt = blockIdx.x;
    const int beg = bucketBase[bkt];
    const int end = bucketBase[bkt + 1];
    for (int i = t; i < BNODES; i += 256) cnt[i] = 0;
    __syncthreads();
    for (int k = beg + t; k < end; k += 256)
        atomicAdd(&cnt[bucketData[k] & (BNODES - 1)], 1);
    __syncthreads();
    int local[4];
    int sum = 0;
#pragma unroll
    for (int j = 0; j < 4; ++j) { local[j] = sum; sum += cnt[t * 4 + j]; }
    sscan[t] = sum;
    __syncthreads();
    for (int off = 1; off < 256; off <<= 1) {
        int v = (t >= off) ? sscan[t - off] : 0;
        __syncthreads();
        sscan[t] += v;
        __syncthreads();
    }
    int base = (t > 0) ? sscan[t - 1] : 0;
#pragma unroll
    for (int j = 0; j < 4; ++j) cur[t * 4 + j] = base + local[j];
    __syncthreads();
    for (int i = t; i < BNODES; i += 256) {
        int node = (bkt << BSHIFT) + i;
        if (node <= N) offsets[node] = beg + cur[i];
    }
    if (bkt == NB - 1 && t == 0 && (NB << BSHIFT) == N) offsets[N] = E;
    __syncthreads();
    for (int k = beg + t; k < end; k += 256) {
        unsigned v = bucketData[k];
        int d   = (int)(v & (BNODES - 1));
        int pos = beg + atomicAdd(&cur[d], 1);
        csr_src[pos] = (int)(v >> BSHIFT);
    }
}

// ---------- fused gather-mean + MFMA dense ----------
// Block = 64 nodes x 64 outs, 4 waves.
// Phase A: gather-mean of featb rows (bf16, fp32 accumulate) for this block's
//          64 nodes directly into A_s k<DIN; self rows copied to k>=DIN.
// Phase B: weights double-bf16 (hi+lo) -> Bh_s/Bl_s rows [o][k]=[Wl[o]|Wr[o]].
// MFMA 16x16x32_bf16; layouts per m89/m91. nSteps RUNTIME (R11 lesson).
// Row stride K+8 -> only free 2-way bank aliasing.

template <int DIN, bool POOL>
__launch_bounds__(256)
__global__ void mfma_fused_kernel(const unsigned short* __restrict__ featb,
                                  const int* __restrict__ csr_src,
                                  const int* __restrict__ offsets,
                                  const float* __restrict__ Wl,
                                  const float* __restrict__ Wr,
                                  const float* __restrict__ bias,
                                  unsigned short* __restrict__ houtb,
                                  const int* __restrict__ batch,
                                  float* __restrict__ pool_sum,
                                  int N, int nSteps) {
    constexpr int K   = 2 * DIN;      // 64 / 128
    constexpr int STR = K + 8;        // 72 / 136 ushorts, rows 16B-aligned
    constexpr int D4  = DIN / 4;
    constexpr int D8  = DIN / 8;      // uint4 chunks per feature row
    __shared__ unsigned short A_s[64 * STR];
    __shared__ unsigned short Bh_s[64 * STR];
    __shared__ unsigned short Bl_s[64 * STR];
    const int tid = threadIdx.x;
    const int nodeBase = blockIdx.x * 64;
    const uint4* fbase = reinterpret_cast<const uint4*>(featb);

    // Phase A1: gather-mean into k [0, DIN). pair = (node, chunk q).
    for (int pairIdx = tid; pairIdx < 64 * D8; pairIdx += 256) {
        const int node = pairIdx / D8;
        const int q    = pairIdx % D8;
        const int n = min(nodeBase + node, N - 1);
        const int beg = offsets[n];
        const int end = offsets[n + 1];
        float a[8] = {0.f, 0.f, 0.f, 0.f, 0.f, 0.f, 0.f, 0.f};
        int k = beg;
        for (; k + 4 <= end; k += 4) {
            const int s0 = csr_src[k + 0];
            const int s1 = csr_src[k + 1];
            const int s2 = csr_src[k + 2];
            const int s3 = csr_src[k + 3];
            const uint4 u0 = fbase[(size_t)s0 * D8 + q];
            const uint4 u1 = fbase[(size_t)s1 * D8 + q];
            const uint4 u2 = fbase[(size_t)s2 * D8 + q];
            const uint4 u3 = fbase[(size_t)s3 * D8 + q];
            acc8(u0, a); acc8(u1, a); acc8(u2, a); acc8(u3, a);
        }
        for (; k < end; ++k)
            acc8(fbase[(size_t)csr_src[k] * D8 + q], a);
        const float inv = 1.0f / fmaxf((float)(end - beg), 1.0f);
        ushort4 lo, hi;
        lo.x = f2bf(a[0] * inv); lo.y = f2bf(a[1] * inv);
        lo.z = f2bf(a[2] * inv); lo.w = f2bf(a[3] * inv);
        hi.x = f2bf(a[4] * inv); hi.y = f2bf(a[5] * inv);
        hi.z = f2bf(a[6] * inv); hi.w = f2bf(a[7] * inv);
        unsigned short* dstp = &A_s[node * STR + q * 8];
        *reinterpret_cast<ushort4*>(dstp)     = lo;
        *reinterpret_cast<ushort4*>(dstp + 4) = hi;
    }
    // Phase A2: self rows into k [DIN, 2*DIN)
    for (int i = tid; i < 64 * D8; i += 256) {
        const int node = i / D8, q = i % D8;
        const int n = min(nodeBase + node, N - 1);
        const uint4 u = fbase[(size_t)n * D8 + q];
        *reinterpret_cast<uint4*>(&A_s[node * STR + DIN + q * 8]) = u;
    }
    // Phase B: weights double-bf16; row o = [Wl[o] | Wr[o]]
    for (int i = tid; i < 64 * D4 * 2; i += 256) {
        const int half = i / (64 * D4);
        const int j = i % (64 * D4);
        const int o = j / D4, c4 = j % D4;
        const float* W = half ? Wr : Wl;
        const float4 v = *reinterpret_cast<const float4*>(W + (size_t)o * DIN + c4 * 4);
        ushort4 hi, lo;
        hi.x = f2bf(v.x); hi.y = f2bf(v.y); hi.z = f2bf(v.z); hi.w = f2bf(v.w);
        lo.x = f2bf(v.x - bf2f(hi.x));
        lo.y = f2bf(v.y - bf2f(hi.y));
        lo.z = f2bf(v.z - bf2f(hi.z));
        lo.w = f2bf(v.w - bf2f(hi.w));
        *reinterpret_cast<ushort4*>(&Bh_s[o * STR + half * DIN + c4 * 4]) = hi;
        *reinterpret_cast<ushort4*>(&Bl_s[o * STR + half * DIN + c4 * 4]) = lo;
    }
    __syncthreads();

    const int lane = tid & 63;
    const int wave = tid >> 6;
    const int lr = lane & 15;        // A: m (node); B: n (out); D: col (out)
    const int q  = lane >> 4;        // frag k-quad; D row group
    f32x4 acc[4];
#pragma unroll
    for (int t = 0; t < 4; ++t) {
        const float b = bias[t * 16 + lr];
        acc[t] = (f32x4){b, b, b, b};
    }
    const unsigned short* Arow = &A_s[(wave * 16 + lr) * STR + q * 8];
    for (int s = 0; s < nSteps; ++s) {    // runtime: no full unroll
        const bf16x8 af = *reinterpret_cast<const bf16x8*>(Arow + s * 32);
#pragma unroll
        for (int t = 0; t < 4; ++t) {
            const int boff = (t * 16 + lr) * STR + s * 32 + q * 8;
            const bf16x8 bh = *reinterpret_cast<const bf16x8*>(&Bh_s[boff]);
            const bf16x8 bl = *reinterpret_cast<const bf16x8*>(&Bl_s[boff]);
            acc[t] = __builtin_amdgcn_mfma_f32_16x16x32_bf16(af, bh, acc[t], 0, 0, 0);
            acc[t] = __builtin_amdgcn_mfma_f32_16x16x32_bf16(af, bl, acc[t], 0, 0, 0);
        }
    }

    // D layout: row(node local 16) = q*4 + reg, col(out) = t*16 + lr
    if (POOL) {
        float ag[4] = {0.f, 0.f, 0.f, 0.f};
        int gcur = -1;
        for (int reg = 0; reg < 4; ++reg) {
            const int n = nodeBase + wave * 16 + q * 4 + reg;
            if (n >= N) break;
            const int g = batch[n];              // sorted
            if (g != gcur) {
                if (gcur >= 0) {
#pragma unroll
                    for (int t = 0; t < 4; ++t)
                        atomicAdd(&pool_sum[(size_t)gcur * 64 + t * 16 + lr], ag[t]);
                }
                gcur = g;
                ag[0] = ag[1] = ag[2] = ag[3] = 0.f;
            }
#pragma unroll
            for (int t = 0; t < 4; ++t)
                ag[t] += fmaxf(acc[t][reg], 0.0f);
        }
        if (gcur >= 0) {
#pragma unroll
            for (int t = 0; t < 4; ++t)
                atomicAdd(&pool_sum[(size_t)gcur * 64 + t * 16 + lr], ag[t]);
        }
    } else {
        for (int reg = 0; reg < 4; ++reg) {
            const int n = nodeBase + wave * 16 + q * 4 + reg;
            if (n >= N) break;
#pragma unroll
            for (int t = 0; t < 4; ++t)
                houtb[(size_t)n * 64 + t * 16 + lr] = f2bf(fmaxf(acc[t][reg], 0.0f));
        }
    }
}

// ---------- head ----------

__global__ void final_kernel(const float* __restrict__ pool_sum,
                             const int* __restrict__ cnt,
                             const float* __restrict__ W_lin,
                             const float* __restrict__ b_lin,
                             float* __restrict__ out, int G) {
    int t = blockIdx.x * blockDim.x + threadIdx.x;
    if (t >= G * 2) return;
    int g = t >> 1, o = t & 1;
    float inv = 1.0f / fmaxf((float)cnt[g], 1.0f);
    float acc = b_lin[o];
#pragma unroll
    for (int c = 0; c < 64; ++c)
        acc = fmaf(pool_sum[(size_t)g * 64 + c] * inv, W_lin[o * 64 + c], acc);
    out[t] = acc;
}

extern "C" void kernel_launch(void* const* d_in, const int* in_sizes, int n_in,
                              void* d_out, int out_size, void* d_ws, size_t ws_size,
                              hipStream_t stream) {
    const float* x     = (const float*)d_in[0];
    const int*   ei    = (const int*)d_in[1];
    const int*   batch = (const int*)d_in[2];
    const float* W1_l  = (const float*)d_in[3];
    const float* b1    = (const float*)d_in[4];
    const float* W1_r  = (const float*)d_in[5];
    const float* W2_l  = (const float*)d_in[6];
    const float* b2    = (const float*)d_in[7];
    const float* W2_r  = (const float*)d_in[8];
    const float* W_lin = (const float*)d_in[9];
    const float* b_lin = (const float*)d_in[10];

    const int N = in_sizes[0] / 32;
    const int E = in_sizes[1] / 2;
    const int G = out_size / 2;
    const int* src = ei;
    const int* dst = ei + E;
    const int NB = (N + BNODES - 1) >> BSHIFT;   // 196 for N=200000

    char* p = (char*)d_ws;
    auto carve = [&](size_t bytes) -> void* {
        void* r = (void*)p;
        p += (bytes + (WS_ALIGN - 1)) / WS_ALIGN * WS_ALIGN;
        return r;
    };
    int*            bucketCount  = (int*)carve(256 * 4);
    int*            bucketBase   = (int*)carve(257 * 4);
    int*            bucketCursor = (int*)carve(256 * 4);
    unsigned*       bucketData   = (unsigned*)carve((size_t)E * 4);
    int*            offsets      = (int*)carve((size_t)(N + 1) * 4);
    int*            csr_src      = (int*)carve((size_t)E * 4);
    unsigned short* xb           = (unsigned short*)carve((size_t)N * 32 * 2);
    unsigned short* h1b          = (unsigned short*)carve((size_t)N * 64 * 2);
    float*          pool         = (float*)carve((size_t)G * 64 * 4);
    int*            cnt          = (int*)carve((size_t)G * 4);
    float*          out          = (float*)d_out;

    hipMemsetAsync(bucketCount, 0, 256 * 4, stream);
    hipMemsetAsync(pool, 0, (size_t)G * 64 * 4, stream);
    hipMemsetAsync(cnt, 0, (size_t)G * 4, stream);

    const int TB = 256;
    cnt_kernel<<<(N + TB - 1) / TB, TB, 0, stream>>>(batch, cnt, N);
    cvt_kernel<<<((N * 32 / 4) + TB - 1) / TB, TB, 0, stream>>>(x, xb, N * 32 / 4);
    bucket_hist_kernel<<<1024, TB, 0, stream>>>(dst, bucketCount, E);
    bucket_scan_kernel<<<1, TB, 0, stream>>>(bucketCount, bucketBase, bucketCursor, NB, E);
    bucket_scatter_kernel<<<(E + EPB - 1) / EPB, TB, 0, stream>>>(src, dst, bucketCursor,
                                                                  bucketData, E, NB);
    csr_build_kernel<<<NB, TB, 0, stream>>>(bucketData, bucketBase, offsets, csr_src, N, E, NB);

    // layer 1: fused gather-mean(xb) + MFMA 32->64 + relu -> h1b (bf16)
    mfma_fused_kernel<32, false><<<(N + 63) / 64, TB, 0, stream>>>(
        xb, csr_src, offsets, W1_l, W1_r, b1, h1b, nullptr, nullptr, N, 2);

    // layer 2: fused gather-mean(h1b) + MFMA 64->64 + relu + pool
    mfma_fused_kernel<64, true><<<(N + 63) / 64, TB, 0, stream>>>(
        h1b, csr_src, offsets, W2_l, W2_r, b2, nullptr, batch, pool, N, 4);

    final_kernel<<<(G * 2 + TB - 1) / TB, TB, 0, stream>>>(pool, cnt, W_lin, b_lin, out, G);
}